// Round 7
// baseline (357.068 us; speedup 1.0000x reference)
//
#include <hip/hip_runtime.h>
#include <math.h>

typedef float4 f4;
typedef __bf16 bf16x8 __attribute__((ext_vector_type(8)));
typedef float f32x4 __attribute__((ext_vector_type(4)));

static constexpr int kV = 10000, kL = 6, kDPL = 500;
static constexpr int kB = 64, kT = 32, kN = 40, kBT = 2048;
static constexpr int kXC = 5;          // xgemm K-chunks (4 x 2048 + 1808)
static constexpr int kNB = 272;        // xgemm out cols (258 useful)
static constexpr int kLd = 10240;      // Btab/coWT k-/n- pad
static constexpr int kVT2 = 40;        // loss v-tiles of 256

#define MFMA16 __builtin_amdgcn_mfma_f32_16x16x32_bf16

typedef const __attribute__((address_space(1))) unsigned int ga_u32;
typedef __attribute__((address_space(3))) unsigned int lds_u32;
__device__ __forceinline__ void gll16(const float* g, float* l) {
  __builtin_amdgcn_global_load_lds((ga_u32*)g, (lds_u32*)l, 16, 0, 0);
}

__device__ __forceinline__ bf16x8 cvt8(f4 a, f4 b) {
  bf16x8 r;
  r[0] = (__bf16)a.x; r[1] = (__bf16)a.y; r[2] = (__bf16)a.z; r[3] = (__bf16)a.w;
  r[4] = (__bf16)b.x; r[5] = (__bf16)b.y; r[6] = (__bf16)b.z; r[7] = (__bf16)b.w;
  return r;
}

// ---------------- fp32 -> bf16 elementwise ----------------
__global__ __launch_bounds__(256) void mmore_cvt_bf16(
    const float* __restrict__ in, __bf16* __restrict__ out, int n) {
  int i = (blockIdx.x * 256 + threadIdx.x) * 8;
  if (i < n) {
    f4 a = *(const f4*)(in + i), b = *(const f4*)(in + i + 4);
    *(bf16x8*)(out + i) = cvt8(a, b);
  }
}

// -------- transpose+cvt: out[n][k] (bf16, k/n-pad zeros) = in[k][n] ---------
__global__ __launch_bounds__(256) void mmore_trcvt(
    const float* __restrict__ in, __bf16* __restrict__ out,
    int K, int N, int Kpad) {
  int t = threadIdx.x;
  int n = blockIdx.y * 16 + (t & 15);
  int kb = (blockIdx.x * 16 + (t >> 4)) * 8;
  bf16x8 r;
  #pragma unroll
  for (int i = 0; i < 8; ++i) {
    int k = kb + i;
    float v = (k < K && n < N) ? in[(size_t)k * N + n] : 0.f;
    r[i] = (__bf16)v;
  }
  *(bf16x8*)(out + (size_t)n * Kpad + kb) = r;
}

// -------- Btab rows 128..271: coW rows (k-contig), cob, ones, zeros ---------
__global__ __launch_bounds__(256) void mmore_brow(
    const float* __restrict__ coW, const float* __restrict__ cob,
    __bf16* __restrict__ Btab) {
  int id = blockIdx.x * 256 + threadIdx.x;
  int rr = id / 1280;               // 0..143
  int kk = (id - rr * 1280) * 8;
  bf16x8 r;
  #pragma unroll
  for (int i = 0; i < 8; ++i) {
    int k = kk + i;
    float v = 0.f;
    if (k < kV) {
      if (rr < 128) v = coW[(size_t)rr * kV + k];
      else if (rr == 128) v = cob[k];
      else if (rr == 129) v = 1.f;
    }
    r[i] = (__bf16)v;
  }
  *(bf16x8*)(Btab + (size_t)(128 + rr) * kLd + kk) = r;
}

// ---------------- ehrV = l2norm(sum_n ehr_table[dxseqs]) ----------------
__global__ __launch_bounds__(128) void mmore_ehrv(
    const int* __restrict__ dxseqs, const float* __restrict__ ehr_table,
    float* __restrict__ ehrV) {
  int bt = blockIdx.x, t = threadIdx.x;
  const int* row = dxseqs + bt * kN;
  float acc = 0.f;
  for (int n = 0; n < kN; ++n) acc += ehr_table[(size_t)row[n] * 128 + t];
  float v = acc * acc;
  #pragma unroll
  for (int off = 32; off; off >>= 1) v += __shfl_down(v, off);
  __shared__ float red[2];
  if ((t & 63) == 0) red[t >> 6] = v;
  __syncthreads();
  float ss = red[0] + red[1];
  float inv = 1.f / fmaxf(sqrtf(ss), 1e-12f);
  ehrV[bt * 128 + t] = acc * inv;
}

// ---------------- GRAM scores via MFMA ----------------
__global__ __launch_bounds__(256) void mmore_scores_mfma(
    const __bf16* __restrict__ otb, const int* __restrict__ leaves,
    const int* __restrict__ anc, const __bf16* __restrict__ WaT,
    const float* __restrict__ ba, const float* __restrict__ Wc,
    const float* __restrict__ bc, float* __restrict__ s_out) {
  int t = threadIdx.x, wave = t >> 6, lane = t & 63, lm = lane & 15, lg = lane >> 4;
  int r0 = blockIdx.x * 32;
  int rA0 = r0 + lm, rA1 = rA0 + 16;
  int v0 = rA0 / 6, l0 = rA0 - v0 * 6, v1 = rA1 / 6, l1 = rA1 - v1 * 6;
  const __bf16* pL0 = otb + (size_t)leaves[v0 * 6 + l0] * 128;
  const __bf16* pA0 = otb + (size_t)anc[v0 * 6 + l0] * 128;
  const __bf16* pL1 = otb + (size_t)leaves[v1 * 6 + l1] * 128;
  const __bf16* pA1 = otb + (size_t)anc[v1 * 6 + l1] * 128;
  const __bf16* bp = WaT + (size_t)(wave * 32 + lm) * 256 + lg * 8;
  f32x4 acc[2][2] = {};
  #pragma unroll
  for (int kb = 0; kb < 256; kb += 32) {
    int k = kb + lg * 8;
    const __bf16* s0 = (k < 128) ? (pL0 + k) : (pA0 + (k - 128));
    const __bf16* s1 = (k < 128) ? (pL1 + k) : (pA1 + (k - 128));
    bf16x8 a0 = *(const bf16x8*)s0;
    bf16x8 a1 = *(const bf16x8*)s1;
    bf16x8 b0 = *(const bf16x8*)(bp + kb);
    bf16x8 b1 = *(const bf16x8*)(bp + kb + 16 * 256);
    acc[0][0] = MFMA16(a0, b0, acc[0][0], 0, 0, 0);
    acc[0][1] = MFMA16(a0, b1, acc[0][1], 0, 0, 0);
    acc[1][0] = MFMA16(a1, b0, acc[1][0], 0, 0, 0);
    acc[1][1] = MFMA16(a1, b1, acc[1][1], 0, 0, 0);
  }
  __shared__ float red[4][32];
  float bcv = bc[0];
  #pragma unroll
  for (int mf = 0; mf < 2; ++mf) {
    #pragma unroll
    for (int j = 0; j < 4; ++j) {
      float p = 0.f;
      #pragma unroll
      for (int nf = 0; nf < 2; ++nf) {
        int c = wave * 32 + nf * 16 + lm;
        p += tanhf(acc[mf][nf][j] + ba[c]) * Wc[c];
      }
      #pragma unroll
      for (int off = 8; off; off >>= 1) p += __shfl_xor(p, off);
      if (lm == 0) red[wave][mf * 16 + lg * 4 + j] = p;
    }
  }
  __syncthreads();
  if (t < 32) s_out[r0 + t] = red[0][t] + red[1][t] + red[2][t] + red[3][t] + bcv;
}

// ---------------- onto_all[v] = softmax_l(s) . ea ; row V = 0 ----------------
__global__ __launch_bounds__(128) void mmore_onto(
    const float* __restrict__ ot, const int* __restrict__ anc,
    const float* __restrict__ s_in, float* __restrict__ onto_all) {
  int v = blockIdx.x, t = threadIdx.x;
  if (v == kV) { onto_all[(size_t)v * 128 + t] = 0.f; return; }
  __shared__ float sv[kL];
  __shared__ int aidx[kL];
  if (t < kL) { sv[t] = s_in[v * kL + t]; aidx[t] = anc[v * kL + t]; }
  __syncthreads();
  float mx = sv[0];
  #pragma unroll
  for (int l = 1; l < kL; ++l) mx = fmaxf(mx, sv[l]);
  float e[kL], sum = 0.f;
  #pragma unroll
  for (int l = 0; l < kL; ++l) { e[l] = expf(sv[l] - mx); sum += e[l]; }
  float acc = 0.f;
  #pragma unroll
  for (int l = 0; l < kL; ++l)
    acc += (e[l] / sum) * ot[(size_t)aidx[l] * 128 + t];
  onto_all[(size_t)v * 128 + t] = acc;
}

// ===== fused X-GEMM v2: part[chunk][bt][272] = X @ Btab^T =====
// BM=32, BK=128, 8 waves: wave w = (kh = w>>2, mf = (w>>1)&1, nh = w&1).
// K halved in-block (kh), M/N split per wave -> 32-36 MFMA per barrier.
// LDS: a_s[kh][dbuf][32 rows][128 fl] = 64 KB, XOR-swizzled granules
// (gl = (G&24)|((G^row)&7)) staged via pre-swizzled global source.
// Grid 64 btiles x 5 chunks, 512 threads.
#define XG_STAGE(db, s)                                                       \
  {                                                                           \
    int kk0_ = kbase + (s) * 128;                                             \
    _Pragma("unroll")                                                         \
    for (int u = 0; u < 4; ++u) {                                             \
      int row_ = u * 8 + g * 2 + s_sub;                                       \
      int sg_ = (s_gr & 24) | ((s_gr ^ row_) & 7);                            \
      gll16(X + (size_t)(r0 + row_) * kV + kk0_ + sg_ * 4,                    \
            &a_s[kh][db][u * 1024 + g * 256]);                                \
    }                                                                         \
  }

#define XG_CSTEP(db, s)                                                       \
  {                                                                           \
    const __bf16* bs_ = bbase + (s) * 128;                                    \
    _Pragma("unroll")                                                         \
    for (int kk = 0; kk < 4; ++kk) {                                          \
      f4 x0_ = *(const f4*)&a_s[kh][db][roff[kk][0]];                         \
      f4 x1_ = *(const f4*)&a_s[kh][db][roff[kk][1]];                         \
      bf16x8 af_ = cvt8(x0_, x1_);                                            \
      _Pragma("unroll")                                                       \
      for (int nf = 0; nf < 8; ++nf) {                                        \
        bf16x8 b_ = *(const bf16x8*)(bs_ + (size_t)(f0 + nf) * 16 * kLd + kk * 32); \
        acc[nf] = MFMA16(af_, b_, acc[nf], 0, 0, 0);                          \
      }                                                                       \
      if (nh) {                                                               \
        bf16x8 b_ = *(const bf16x8*)(bs_ + (size_t)256 * kLd + kk * 32);      \
        acc8 = MFMA16(af_, b_, acc8, 0, 0, 0);                                \
      }                                                                       \
    }                                                                         \
  }

__global__ __launch_bounds__(512) void mmore_xgemm(
    const float* __restrict__ X, const __bf16* __restrict__ Btab,
    float* __restrict__ part) {
  __shared__ __align__(16) float a_s[2][2][32 * 128];   // 64 KB
  int t = threadIdx.x;
  int w = t >> 6, lane = t & 63, lm = lane & 15, lg = lane >> 4;
  int kh = w >> 2, mf = (w >> 1) & 1, nh = w & 1, g = w & 3;
  int btile = blockIdx.x & 63, chunk = blockIdx.x >> 6;
  int r0 = btile * 32;
  bool lastc = (chunk == kXC - 1);
  int kbase = lastc ? (8192 + kh * 896) : (chunk * 2048 + kh * 1024);
  int nsteps = lastc ? 7 : 8;
  int arow = mf * 16 + lm;
  int f0 = nh * 8;
  int s_sub = lane >> 5, s_gr = lane & 31;
  const __bf16* bbase = Btab + (size_t)lm * kLd + kbase + lg * 8;
  // swizzled LDS read offsets (floats), static-indexed only
  int roff[4][2];
  #pragma unroll
  for (int kk = 0; kk < 4; ++kk)
    #pragma unroll
    for (int h = 0; h < 2; ++h) {
      int G = kk * 8 + lg * 2 + h;
      int gl = (G & 24) | ((G ^ arow) & 7);
      roff[kk][h] = arow * 128 + gl * 4;
    }
  f32x4 acc[8] = {};
  f32x4 acc8 = {};

  XG_STAGE(0, 0);
  __syncthreads();
  int db = 0;
  for (int s = 0; s < nsteps; ++s) {
    if (s + 1 < nsteps) XG_STAGE(db ^ 1, s + 1);
    XG_CSTEP(db, s);
    asm volatile("s_waitcnt vmcnt(0)" ::: "memory");
    __builtin_amdgcn_s_barrier();
    db ^= 1;
  }
  if (lastc && kh == 1) {  // tail k 9984..9999 (Btab zero-padded past 10000)
    f4 z = make_float4(0.f, 0.f, 0.f, 0.f), x0 = z, x1 = z;
    if (lg < 2) {
      const float* xp = X + (size_t)(r0 + arow) * kV + 9984 + lg * 8;
      x0 = *(const f4*)xp; x1 = *(const f4*)(xp + 4);
    }
    bf16x8 af = cvt8(x0, x1);
    const __bf16* bs = Btab + (size_t)lm * kLd + 9984 + lg * 8;
    #pragma unroll
    for (int nf = 0; nf < 8; ++nf) {
      bf16x8 b = *(const bf16x8*)(bs + (size_t)(f0 + nf) * 16 * kLd);
      acc[nf] = MFMA16(af, b, acc[nf], 0, 0, 0);
    }
    if (nh) {
      bf16x8 b = *(const bf16x8*)(bs + (size_t)256 * kLd);
      acc8 = MFMA16(af, b, acc8, 0, 0, 0);
    }
  }
  // ---- cross-half reduce (kh1 -> LDS, kh0 adds & writes) ----
  __syncthreads();
  float* red = &a_s[0][0][0];   // 32 x 272 fp32 = 34 KB
  if (kh == 1) {
    #pragma unroll
    for (int nf = 0; nf < 8; ++nf)
      #pragma unroll
      for (int j = 0; j < 4; ++j)
        red[(mf * 16 + lg * 4 + j) * kNB + (f0 + nf) * 16 + lm] = acc[nf][j];
    if (nh)
      #pragma unroll
      for (int j = 0; j < 4; ++j)
        red[(mf * 16 + lg * 4 + j) * kNB + 256 + lm] = acc8[j];
  }
  __syncthreads();
  if (kh == 0) {
    #pragma unroll
    for (int j = 0; j < 4; ++j) {
      int row = mf * 16 + lg * 4 + j;
      int r = r0 + row;
      int bt = (r & 63) * kT + (r >> 6);   // memory row -> bt index
      size_t o = ((size_t)chunk * kBT + bt) * kNB;
      #pragma unroll
      for (int nf = 0; nf < 8; ++nf) {
        int col = (f0 + nf) * 16 + lm;
        part[o + col] = acc[nf][j] + red[row * kNB + col];
      }
      if (nh) part[o + 256 + lm] = acc8[j] + red[row * kNB + 256 + lm];
    }
  }
}

// ----- creduce: sum 5 chunk-partials -> ontoV / pwred / pc / sp -------------
__global__ __launch_bounds__(256) void mmore_creduce(
    const float* __restrict__ part, float* __restrict__ ontoV,
    float* __restrict__ pwred, float* __restrict__ pc, float* __restrict__ sp) {
  int bt = blockIdx.x, t = threadIdx.x;
  for (int c = t; c < kNB; c += 256) {
    float a = 0.f;
    #pragma unroll
    for (int ch = 0; ch < kXC; ++ch)
      a += part[((size_t)ch * kBT + bt) * kNB + c];
    if (c < 128) ontoV[(size_t)bt * 128 + c] = a;
    else if (c < 256) pwred[(size_t)bt * 128 + (c - 128)] = a;
    else if (c == 256) pc[bt] = a;
    else if (c == 257) sp[bt] = a;
  }
}

// ----- loss GEMM: epart[vt][bt] = sum_{c in vtile} e^(ehrV@coW + cob) -------
__global__ __launch_bounds__(256) void mmore_lossg(
    const float* __restrict__ ehrV, const __bf16* __restrict__ coWT,
    const float* __restrict__ cob, float* __restrict__ epart) {
  int t = threadIdx.x, wave = t >> 6, lane = t & 63, lm = lane & 15, lg = lane >> 4;
  int vt = blockIdx.x, btile = blockIdx.y;
  int r0 = btile * 32, vb = vt * 256;
  const float* a0 = ehrV + (size_t)(r0 + lm) * 128 + lg * 8;
  const float* a1 = a0 + 16 * 128;
  f32x4 acc[2][4] = {};
  #pragma unroll
  for (int kb = 0; kb < 128; kb += 32) {
    f4 x0 = *(const f4*)(a0 + kb), x1 = *(const f4*)(a0 + kb + 4);
    f4 y0 = *(const f4*)(a1 + kb), y1 = *(const f4*)(a1 + kb + 4);
    bf16x8 af0 = cvt8(x0, x1), af1 = cvt8(y0, y1);
    #pragma unroll
    for (int nf = 0; nf < 4; ++nf) {
      int c = vb + wave * 64 + nf * 16 + lm;
      bf16x8 b = *(const bf16x8*)(coWT + (size_t)c * 128 + kb + lg * 8);
      acc[0][nf] = MFMA16(af0, b, acc[0][nf], 0, 0, 0);
      acc[1][nf] = MFMA16(af1, b, acc[1][nf], 0, 0, 0);
    }
  }
  float se[2][4] = {};
  #pragma unroll
  for (int nf = 0; nf < 4; ++nf) {
    int c = vb + wave * 64 + nf * 16 + lm;
    if (c < kV) {
      float cb = cob[c];
      #pragma unroll
      for (int mf = 0; mf < 2; ++mf)
        #pragma unroll
        for (int j = 0; j < 4; ++j)
          se[mf][j] += __expf(acc[mf][nf][j] + cb);
    }
  }
  __shared__ float red[4][32];
  #pragma unroll
  for (int mf = 0; mf < 2; ++mf)
    #pragma unroll
    for (int j = 0; j < 4; ++j) {
      float v = se[mf][j];
      #pragma unroll
      for (int off = 8; off; off >>= 1) v += __shfl_xor(v, off);
      if (lm == 0) red[wave][mf * 16 + lg * 4 + j] = v;
    }
  __syncthreads();
  if (t < 32)
    epart[(size_t)vt * kBT + r0 + t] =
        red[0][t] + red[1][t] + red[2][t] + red[3][t];
}

// ----- lossterm: term[bt] = (ehrV.pwred + pc) - sp*log(sum epart) -----------
__global__ __launch_bounds__(256) void mmore_lossterm(
    const float* __restrict__ ehrV, const float* __restrict__ pwred,
    const float* __restrict__ pc, const float* __restrict__ sp,
    const float* __restrict__ epart, float* __restrict__ term) {
  int t = threadIdx.x;
  int bt = blockIdx.x * 16 + (t >> 4);
  int sub = t & 15;
  const f4* e = (const f4*)(ehrV + (size_t)bt * 128 + sub * 8);
  const f4* w = (const f4*)(pwred + (size_t)bt * 128 + sub * 8);
  f4 e0 = e[0], e1 = e[1], w0 = w[0], w1 = w[1];
  float d = e0.x * w0.x + e0.y * w0.y + e0.z * w0.z + e0.w * w0.w +
            e1.x * w1.x + e1.y * w1.y + e1.z * w1.z + e1.w * w1.w;
  float S = 0.f;
  for (int vt = sub; vt < kVT2; vt += 16) S += epart[(size_t)vt * kBT + bt];
  #pragma unroll
  for (int off = 8; off; off >>= 1) {
    d += __shfl_xor(d, off); S += __shfl_xor(S, off);
  }
  if (sub == 0) term[bt] = (d + pc[bt]) - sp[bt] * logf(S);
}

__global__ __launch_bounds__(256) void mmore_lossfin(
    const float* __restrict__ term, float* __restrict__ out) {
  int t = threadIdx.x;
  float a = 0.f;
  for (int i = t; i < kBT; i += 256) a += term[i];
  #pragma unroll
  for (int off = 32; off; off >>= 1) a += __shfl_down(a, off);
  __shared__ float red[4];
  if ((t & 63) == 0) red[t >> 6] = a;
  __syncthreads();
  if (t == 0) out[0] = -(10.f / 64.f) * (red[0] + red[1] + red[2] + red[3]);
}

// ---------------- generic MFMA: C[M][128] (+=) A[M][128] @ WT[n][ldWT]+koff --
__global__ __launch_bounds__(256) void mmore_gemm_mfma(
    const float* __restrict__ A, const __bf16* __restrict__ WT,
    int ldWT, int koff, const float* __restrict__ bias,
    float* __restrict__ C, int M, int accumulate) {
  int t = threadIdx.x, wave = t >> 6, lane = t & 63, lm = lane & 15, lg = lane >> 4;
  int r0 = blockIdx.x * 32;
  int row0 = r0 + lm, row1 = row0 + 16;
  bool ok0 = row0 < M, ok1 = row1 < M;
  const float* a0 = A + (size_t)row0 * 128 + lg * 8;
  const float* a1 = A + (size_t)row1 * 128 + lg * 8;
  const __bf16* bp = WT + (size_t)(wave * 32 + lm) * ldWT + koff + lg * 8;
  int ld16 = 16 * ldWT;
  f32x4 acc[2][2] = {};
  #pragma unroll
  for (int kb = 0; kb < 128; kb += 32) {
    f4 x0 = make_float4(0, 0, 0, 0), x1 = x0, y0 = x0, y1 = x0;
    if (ok0) { x0 = *(const f4*)(a0 + kb); x1 = *(const f4*)(a0 + kb + 4); }
    if (ok1) { y0 = *(const f4*)(a1 + kb); y1 = *(const f4*)(a1 + kb + 4); }
    bf16x8 af0 = cvt8(x0, x1), af1 = cvt8(y0, y1);
    bf16x8 b0 = *(const bf16x8*)(bp + kb);
    bf16x8 b1 = *(const bf16x8*)(bp + kb + ld16);
    acc[0][0] = MFMA16(af0, b0, acc[0][0], 0, 0, 0);
    acc[0][1] = MFMA16(af0, b1, acc[0][1], 0, 0, 0);
    acc[1][0] = MFMA16(af1, b0, acc[1][0], 0, 0, 0);
    acc[1][1] = MFMA16(af1, b1, acc[1][1], 0, 0, 0);
  }
  #pragma unroll
  for (int mf = 0; mf < 2; ++mf)
    #pragma unroll
    for (int nf = 0; nf < 2; ++nf) {
      int col = wave * 32 + nf * 16 + lm;
      #pragma unroll
      for (int j = 0; j < 4; ++j) {
        int row = r0 + mf * 16 + lg * 4 + j;
        if (row < M) {
          float v = acc[mf][nf][j];
          if (bias) v += bias[col];
          if (accumulate) v += C[(size_t)row * 128 + col];
          C[(size_t)row * 128 + col] = v;
        }
      }
    }
}

// ---------------- per-(b,t): Bahdanau attention -> tn = tanh(l2norm(vs2)) ----
__device__ __forceinline__ float mmore_block_sum(float v, float* red) {
  int t = threadIdx.x;
  #pragma unroll
  for (int off = 32; off; off >>= 1) v += __shfl_down(v, off);
  if ((t & 63) == 0) red[t >> 6] = v;
  __syncthreads();
  if (t == 0) red[0] = red[0] + red[1] + red[2] + red[3];
  __syncthreads();
  return red[0];
}

__global__ __launch_bounds__(256) void mmore_attn(
    const int* __restrict__ dxseqs, const float* __restrict__ base,
    const float* __restrict__ pe, const float* __restrict__ po,
    const float* __restrict__ combW, const float* __restrict__ combB,
    const float* __restrict__ ehr_table, const float* __restrict__ onto_all,
    float* __restrict__ tn) {
  __shared__ float base_s[128];
  __shared__ int idx_s[kN];
  __shared__ float scp[kN][2];
  __shared__ float attn_s[64];
  __shared__ float red[4];
  int bt = blockIdx.x, t = threadIdx.x;
  if (t < 128) base_s[t] = base[bt * 128 + t];
  if (t < kN) idx_s[t] = dxseqs[bt * kN + t];
  __syncthreads();
  int c = t & 127, half = t >> 7, wid = t >> 6, lane = t & 63;
  float cw = combW[c];
  for (int n2 = 0; n2 < kN / 2; ++n2) {
    int n = n2 * 2 + half;
    int id = idx_s[n];
    float x = base_s[c] + pe[(size_t)id * 128 + c] + po[(size_t)id * 128 + c];
    float val = tanhf(x) * cw;
    #pragma unroll
    for (int off = 32; off; off >>= 1) val += __shfl_down(val, off);
    if (lane == 0) scp[n][wid & 1] = val;
  }
  __syncthreads();
  if (t < 64) {
    float s = (t < kN) ? (scp[t][0] + scp[t][1] + combB[0]) : -1e30f;
    float mx = s;
    #pragma unroll
    for (int off = 32; off; off >>= 1) mx = fmaxf(mx, __shfl_xor(mx, off));
    float e = (t < kN) ? __expf(s - mx) : 0.f;
    float sm = e;
    #pragma unroll
    for (int off = 32; off; off >>= 1) sm += __shfl_xor(sm, off);
    attn_s[t] = e / sm;
  }
  __syncthreads();
  float acc = 0.f;
  {
    const float* tab = (t < 128) ? ehr_table : onto_all;
    int j = t & 127;
    for (int n = 0; n < kN; ++n)
      acc += attn_s[n] * tab[(size_t)idx_s[n] * 128 + j];
  }
  float ss = mmore_block_sum(acc * acc, red);
  float inv = 1.f / fmaxf(sqrtf(ss), 1e-12f);
  tn[(size_t)bt * 256 + t] = tanhf(acc * inv);
}

// ---------------- dp head GEMM: u[2048][512] = tn@dpWT + dpB ----------------
__global__ __launch_bounds__(256) void mmore_dpgemm(
    const float* __restrict__ tn, const __bf16* __restrict__ dpWT,
    const float* __restrict__ dpB, float* __restrict__ u) {
  int t = threadIdx.x, wave = t >> 6, lane = t & 63, lm = lane & 15, lg = lane >> 4;
  int c0 = blockIdx.x * 128, r0 = blockIdx.y * 32;
  const float* a0 = tn + (size_t)(r0 + lm) * 256 + lg * 8;
  const float* a1 = a0 + 16 * 256;
  const __bf16* bp = dpWT + (size_t)(c0 + wave * 32 + lm) * 256 + lg * 8;
  f32x4 acc[2][2] = {};
  #pragma unroll
  for (int kb = 0; kb < 256; kb += 32) {
    f4 x0 = *(const f4*)(a0 + kb), x1 = *(const f4*)(a0 + kb + 4);
    f4 y0 = *(const f4*)(a1 + kb), y1 = *(const f4*)(a1 + kb + 4);
    bf16x8 af0 = cvt8(x0, x1), af1 = cvt8(y0, y1);
    bf16x8 b0 = *(const bf16x8*)(bp + kb);
    bf16x8 b1 = *(const bf16x8*)(bp + kb + 16 * 256);
    acc[0][0] = MFMA16(af0, b0, acc[0][0], 0, 0, 0);
    acc[0][1] = MFMA16(af0, b1, acc[0][1], 0, 0, 0);
    acc[1][0] = MFMA16(af1, b0, acc[1][0], 0, 0, 0);
    acc[1][1] = MFMA16(af1, b1, acc[1][1], 0, 0, 0);
  }
  #pragma unroll
  for (int mf = 0; mf < 2; ++mf)
    #pragma unroll
    for (int nf = 0; nf < 2; ++nf) {
      int col = c0 + wave * 32 + nf * 16 + lm;
      float bias = (col < kDPL) ? dpB[col] : 0.f;
      #pragma unroll
      for (int j = 0; j < 4; ++j) {
        int row = r0 + mf * 16 + lg * 4 + j;
        u[(size_t)row * 512 + col] = acc[mf][nf][j] + bias;
      }
    }
}

// ---------------- dp softmax over 500 cols ----------------
__global__ __launch_bounds__(128) void mmore_dpsoft(
    const float* __restrict__ u, float* __restrict__ out) {
  int bt = blockIdx.x, t = threadIdx.x;
  __shared__ float red[2];
  float v[4]; float mx = -1e30f;
  #pragma unroll
  for (int i = 0; i < 4; ++i) {
    int c = t + i * 128;
    v[i] = (c < kDPL) ? u[(size_t)bt * 512 + c] : -1e30f;
    mx = fmaxf(mx, v[i]);
  }
  #pragma unroll
  for (int off = 32; off; off >>= 1) mx = fmaxf(mx, __shfl_xor(mx, off));
  if ((t & 63) == 0) red[t >> 6] = mx;
  __syncthreads();
  mx = fmaxf(red[0], red[1]);
  __syncthreads();
  float e[4], s = 0.f;
  #pragma unroll
  for (int i = 0; i < 4; ++i) {
    int c = t + i * 128;
    e[i] = (c < kDPL) ? __expf(v[i] - mx) : 0.f;
    s += e[i];
  }
  #pragma unroll
  for (int off = 32; off; off >>= 1) s += __shfl_xor(s, off);
  if ((t & 63) == 0) red[t >> 6] = s;
  __syncthreads();
  float invS = 1.f / (red[0] + red[1]);
  #pragma unroll
  for (int i = 0; i < 4; ++i) {
    int c = t + i * 128;
    if (c < kDPL) out[(size_t)bt * kDPL + c] = e[i] * invS;
  }
}

extern "C" void kernel_launch(void* const* d_in, const int* in_sizes, int n_in,
                              void* d_out, int out_size, void* d_ws, size_t ws_size,
                              hipStream_t stream) {
  const int*   dxseqs     = (const int*)d_in[0];
  const float* dx_onehot  = (const float*)d_in[1];
  const int*   leaves     = (const int*)d_in[2];
  const int*   ancestors  = (const int*)d_in[3];
  const float* onto_table = (const float*)d_in[4];
  const float* onto_Wa    = (const float*)d_in[5];
  const float* onto_ba    = (const float*)d_in[6];
  const float* onto_Wc    = (const float*)d_in[7];
  const float* onto_bc    = (const float*)d_in[8];
  const float* ehr_table  = (const float*)d_in[9];
  const float* attn_W     = (const float*)d_in[10];
  const float* attn_b     = (const float*)d_in[11];
  const float* comb_W     = (const float*)d_in[12];
  const float* comb_b     = (const float*)d_in[13];
  const float* co_W       = (const float*)d_in[14];
  const float* co_b       = (const float*)d_in[15];
  const float* dp_W       = (const float*)d_in[16];
  const float* dp_b       = (const float*)d_in[17];
  float* out = (float*)d_out;

  // ---- workspace (~26.2 MB) ----
  float* ws = (float*)d_ws;
  size_t off = 0;
  auto alloc = [&](size_t n) { float* p = ws + off; off += n; return p; };
  float* onto_all = alloc((size_t)(kV + 1) * 128);             // 1,280,128
  float* s_sc     = alloc((size_t)kV * kL);                    //    60,000
  float* ehrV     = alloc((size_t)kBT * 128);                  //   262,144
  float* ontoV    = alloc((size_t)kBT * 128);                  //   262,144
  __bf16* Btab    = (__bf16*)alloc((size_t)kNB * kLd / 2);     // 1,392,640 fl
  __bf16* attn_WT = (__bf16*)alloc((size_t)128 * 512 / 2);     //    32,768 fl
  __bf16* dpWT    = (__bf16*)alloc((size_t)512 * 256 / 2);     //    65,536 fl
  __bf16* WaT     = (__bf16*)alloc((size_t)128 * 256 / 2);     //    16,384 fl
  float* peR      = alloc((size_t)(kV + 1) * 128);             // 1,280,128
  float* poR      = alloc((size_t)(kV + 1) * 128);             // 1,280,128
  float* basep    = alloc((size_t)kBT * 128);                  //   262,144
  float* epart    = alloc((size_t)kVT2 * kBT);                 //    81,920
  float* pwred    = alloc((size_t)kBT * 128);                  //   262,144
  float* pc       = alloc(kBT);                                //     2,048
  float* sp       = alloc(kBT);                                //     2,048
  float* term     = alloc(kBT);                                //     2,048
  // time-disjoint aliases in the peR..basep span (2,822,400 fl):
  __bf16* ot_bf = (__bf16*)peR;  // scores input; dead before xgemm
  float*  cpart = peR;           // xgemm partials (2,785,280 fl); dead after creduce
  __bf16* coWT  = (__bf16*)peR;  // loss B (655,360 fl); built after creduce,
                                 // dead before pe-gemm writes peR
  float*  u     = peR;           // dp logits; written after attn reads peR
  float*  tn    = ehrV;          // attn out; written after last ehrV/ontoV reads

  // ---- prep ----
  mmore_cvt_bf16<<<663, 256, 0, stream>>>(onto_table, ot_bf, 10600 * 128);
  mmore_trcvt<<<dim3(2, 8), 256, 0, stream>>>(onto_Wa, WaT, 256, 128, 256);
  mmore_trcvt<<<dim3(4, 8), 256, 0, stream>>>(attn_W, attn_WT, 512, 128, 512);
  mmore_trcvt<<<dim3(2, 32), 256, 0, stream>>>(dp_W, dpWT, 256, kDPL, 256);

  mmore_ehrv<<<kBT, 128, 0, stream>>>(dxseqs, ehr_table, ehrV);
  mmore_scores_mfma<<<(kV * kL) / 32, 256, 0, stream>>>(
      ot_bf, leaves, ancestors, WaT, onto_ba, onto_Wc, onto_bc, s_sc);
  mmore_onto<<<kV + 1, 128, 0, stream>>>(onto_table, ancestors, s_sc, onto_all);
  mmore_trcvt<<<dim3(80, 8), 256, 0, stream>>>(onto_all, Btab, kV, 128, kLd);
  mmore_brow<<<720, 256, 0, stream>>>(co_W, co_b, Btab);
  mmore_xgemm<<<64 * kXC, 512, 0, stream>>>(dx_onehot, Btab, cpart);
  mmore_creduce<<<kBT, 256, 0, stream>>>(cpart, ontoV, pwred, pc, sp);
  mmore_trcvt<<<dim3(1, 640), 256, 0, stream>>>(co_W, coWT, 128, kV, 128);
  mmore_lossg<<<dim3(kVT2, 64), 256, 0, stream>>>(ehrV, coWT, co_b, epart);
  mmore_lossterm<<<kBT / 16, 256, 0, stream>>>(ehrV, pwred, pc, sp, epart, term);
  mmore_lossfin<<<1, 256, 0, stream>>>(term, out + (size_t)kBT * kDPL);
  mmore_gemm_mfma<<<313, 256, 0, stream>>>(ehr_table, attn_WT, 512, 256, nullptr, peR, kV + 1, 0);
  mmore_gemm_mfma<<<313, 256, 0, stream>>>(onto_all, attn_WT, 512, 384, nullptr, poR, kV + 1, 0);
  mmore_gemm_mfma<<<64, 256, 0, stream>>>(ontoV, attn_WT, 512, 0, nullptr, basep, kBT, 0);
  mmore_gemm_mfma<<<64, 256, 0, stream>>>(ehrV, attn_WT, 512, 128, attn_b, basep, kBT, 1);
  mmore_attn<<<kBT, 256, 0, stream>>>(dxseqs, basep, peR, poR, comb_W, comb_b,
                                      ehr_table, onto_all, tn);
  mmore_dpgemm<<<dim3(4, 64), 256, 0, stream>>>(tn, dpWT, dp_b, u);
  mmore_dpsoft<<<kBT, 128, 0, stream>>>(u, out);
}

// Round 8
// 304.576 us; speedup vs baseline: 1.1723x; 1.1723x over previous
//
#include <hip/hip_runtime.h>
#include <math.h>

typedef float4 f4;
typedef __bf16 bf16x8 __attribute__((ext_vector_type(8)));
typedef float f32x4 __attribute__((ext_vector_type(4)));

static constexpr int kV = 10000, kL = 6, kDPL = 500;
static constexpr int kB = 64, kT = 32, kN = 40, kBT = 2048;
static constexpr int kXC = 5;          // xgemm K-chunks (4 x 2048 + 1824)
static constexpr int kNB = 272;        // xgemm out cols (258 useful)
static constexpr int kLd = 10240;      // Btab/coWT k-/n- pad
static constexpr int kNP = 313;        // panels (10016 k padded)
static constexpr int kVT2 = 40;        // loss v-tiles of 256

#define MFMA16 __builtin_amdgcn_mfma_f32_16x16x32_bf16

__device__ __forceinline__ bf16x8 cvt8(f4 a, f4 b) {
  bf16x8 r;
  r[0] = (__bf16)a.x; r[1] = (__bf16)a.y; r[2] = (__bf16)a.z; r[3] = (__bf16)a.w;
  r[4] = (__bf16)b.x; r[5] = (__bf16)b.y; r[6] = (__bf16)b.z; r[7] = (__bf16)b.w;
  return r;
}

// ---------------- fp32 -> bf16 elementwise ----------------
__global__ __launch_bounds__(256) void mmore_cvt_bf16(
    const float* __restrict__ in, __bf16* __restrict__ out, int n) {
  int i = (blockIdx.x * 256 + threadIdx.x) * 8;
  if (i < n) {
    f4 a = *(const f4*)(in + i), b = *(const f4*)(in + i + 4);
    *(bf16x8*)(out + i) = cvt8(a, b);
  }
}

// -------- transpose+cvt: out[n][k] (bf16, k/n-pad zeros) = in[k][n] ---------
__global__ __launch_bounds__(256) void mmore_trcvt(
    const float* __restrict__ in, __bf16* __restrict__ out,
    int K, int N, int Kpad) {
  int t = threadIdx.x;
  int n = blockIdx.y * 16 + (t & 15);
  int kb = (blockIdx.x * 16 + (t >> 4)) * 8;
  bf16x8 r;
  #pragma unroll
  for (int i = 0; i < 8; ++i) {
    int k = kb + i;
    float v = (k < K && n < N) ? in[(size_t)k * N + n] : 0.f;
    r[i] = (__bf16)v;
  }
  *(bf16x8*)(out + (size_t)n * Kpad + kb) = r;
}

// -------- Btab rows 128..271: coW rows (k-contig), cob, ones, zeros ---------
__global__ __launch_bounds__(256) void mmore_brow(
    const float* __restrict__ coW, const float* __restrict__ cob,
    __bf16* __restrict__ Btab) {
  int id = blockIdx.x * 256 + threadIdx.x;
  int rr = id / 1280;               // 0..143
  int kk = (id - rr * 1280) * 8;
  bf16x8 r;
  #pragma unroll
  for (int i = 0; i < 8; ++i) {
    int k = kk + i;
    float v = 0.f;
    if (k < kV) {
      if (rr < 128) v = coW[(size_t)rr * kV + k];
      else if (rr == 128) v = cob[k];
      else if (rr == 129) v = 1.f;
    }
    r[i] = (__bf16)v;
  }
  *(bf16x8*)(Btab + (size_t)(128 + rr) * kLd + kk) = r;
}

// -------- panelize: Bp[S][272][32] = Btab[row][S*32+kk] ---------------------
__global__ __launch_bounds__(256) void mmore_panelize(
    const __bf16* __restrict__ Btab, __bf16* __restrict__ Bp) {
  int t = threadIdx.x;
  int S = blockIdx.x, ry = blockIdx.y;
  int row = ry * 16 + (t >> 4), kk = (t & 15) * 2;
  unsigned v = *(const unsigned*)(Btab + (size_t)row * kLd + S * 32 + kk);
  *(unsigned*)(Bp + ((size_t)S * kNB + row) * 32 + kk) = v;
}

// ---------------- ehrV = l2norm(sum_n ehr_table[dxseqs]) ----------------
__global__ __launch_bounds__(128) void mmore_ehrv(
    const int* __restrict__ dxseqs, const float* __restrict__ ehr_table,
    float* __restrict__ ehrV) {
  int bt = blockIdx.x, t = threadIdx.x;
  const int* row = dxseqs + bt * kN;
  float acc = 0.f;
  for (int n = 0; n < kN; ++n) acc += ehr_table[(size_t)row[n] * 128 + t];
  float v = acc * acc;
  #pragma unroll
  for (int off = 32; off; off >>= 1) v += __shfl_down(v, off);
  __shared__ float red[2];
  if ((t & 63) == 0) red[t >> 6] = v;
  __syncthreads();
  float ss = red[0] + red[1];
  float inv = 1.f / fmaxf(sqrtf(ss), 1e-12f);
  ehrV[bt * 128 + t] = acc * inv;
}

// ---------------- GRAM scores via MFMA ----------------
__global__ __launch_bounds__(256) void mmore_scores_mfma(
    const __bf16* __restrict__ otb, const int* __restrict__ leaves,
    const int* __restrict__ anc, const __bf16* __restrict__ WaT,
    const float* __restrict__ ba, const float* __restrict__ Wc,
    const float* __restrict__ bc, float* __restrict__ s_out) {
  int t = threadIdx.x, wave = t >> 6, lane = t & 63, lm = lane & 15, lg = lane >> 4;
  int r0 = blockIdx.x * 32;
  int rA0 = r0 + lm, rA1 = rA0 + 16;
  int v0 = rA0 / 6, l0 = rA0 - v0 * 6, v1 = rA1 / 6, l1 = rA1 - v1 * 6;
  const __bf16* pL0 = otb + (size_t)leaves[v0 * 6 + l0] * 128;
  const __bf16* pA0 = otb + (size_t)anc[v0 * 6 + l0] * 128;
  const __bf16* pL1 = otb + (size_t)leaves[v1 * 6 + l1] * 128;
  const __bf16* pA1 = otb + (size_t)anc[v1 * 6 + l1] * 128;
  const __bf16* bp = WaT + (size_t)(wave * 32 + lm) * 256 + lg * 8;
  f32x4 acc[2][2] = {};
  #pragma unroll
  for (int kb = 0; kb < 256; kb += 32) {
    int k = kb + lg * 8;
    const __bf16* s0 = (k < 128) ? (pL0 + k) : (pA0 + (k - 128));
    const __bf16* s1 = (k < 128) ? (pL1 + k) : (pA1 + (k - 128));
    bf16x8 a0 = *(const bf16x8*)s0;
    bf16x8 a1 = *(const bf16x8*)s1;
    bf16x8 b0 = *(const bf16x8*)(bp + kb);
    bf16x8 b1 = *(const bf16x8*)(bp + kb + 16 * 256);
    acc[0][0] = MFMA16(a0, b0, acc[0][0], 0, 0, 0);
    acc[0][1] = MFMA16(a0, b1, acc[0][1], 0, 0, 0);
    acc[1][0] = MFMA16(a1, b0, acc[1][0], 0, 0, 0);
    acc[1][1] = MFMA16(a1, b1, acc[1][1], 0, 0, 0);
  }
  __shared__ float red[4][32];
  float bcv = bc[0];
  #pragma unroll
  for (int mf = 0; mf < 2; ++mf) {
    #pragma unroll
    for (int j = 0; j < 4; ++j) {
      float p = 0.f;
      #pragma unroll
      for (int nf = 0; nf < 2; ++nf) {
        int c = wave * 32 + nf * 16 + lm;
        p += tanhf(acc[mf][nf][j] + ba[c]) * Wc[c];
      }
      #pragma unroll
      for (int off = 8; off; off >>= 1) p += __shfl_xor(p, off);
      if (lm == 0) red[wave][mf * 16 + lg * 4 + j] = p;
    }
  }
  __syncthreads();
  if (t < 32) s_out[r0 + t] = red[0][t] + red[1][t] + red[2][t] + red[3][t] + bcv;
}

// ---------------- onto_all[v] = softmax_l(s) . ea ; row V = 0 ----------------
__global__ __launch_bounds__(128) void mmore_onto(
    const float* __restrict__ ot, const int* __restrict__ anc,
    const float* __restrict__ s_in, float* __restrict__ onto_all) {
  int v = blockIdx.x, t = threadIdx.x;
  if (v == kV) { onto_all[(size_t)v * 128 + t] = 0.f; return; }
  __shared__ float sv[kL];
  __shared__ int aidx[kL];
  if (t < kL) { sv[t] = s_in[v * kL + t]; aidx[t] = anc[v * kL + t]; }
  __syncthreads();
  float mx = sv[0];
  #pragma unroll
  for (int l = 1; l < kL; ++l) mx = fmaxf(mx, sv[l]);
  float e[kL], sum = 0.f;
  #pragma unroll
  for (int l = 0; l < kL; ++l) { e[l] = expf(sv[l] - mx); sum += e[l]; }
  float acc = 0.f;
  #pragma unroll
  for (int l = 0; l < kL; ++l)
    acc += (e[l] / sum) * ot[(size_t)aidx[l] * 128 + t];
  onto_all[(size_t)v * 128 + t] = acc;
}

// ===== fused X-GEMM v3: part[chunk][bt][272] = X @ Bp (panelized B) =========
// Direct-load streamer: NO LDS, NO barriers. BM=16, 4 waves; wave w owns
// col-frags w*4..w*4+3 (+frag 16 on wave 3). B loads are 1KB contiguous
// (panel layout); A loads are 16x40KB-strided 64B lines (full line use).
// Grid 128 btiles x 5 chunks = 640 blocks, XCD-swizzled (640%8==0).
__global__ __launch_bounds__(256) void mmore_xgemm(
    const float* __restrict__ X, const __bf16* __restrict__ Bp,
    float* __restrict__ part) {
  int t = threadIdx.x, w = t >> 6, lane = t & 63, lm = lane & 15, lg = lane >> 4;
  int bid = blockIdx.x;
  int swz = (bid & 7) * 80 + (bid >> 3);     // bijective XCD swizzle
  int btile = swz & 127, chunk = swz >> 7;
  int r0 = btile * 16;
  bool lastc = (chunk == kXC - 1);
  int nsteps = lastc ? 56 : 64;
  int f0 = w * 4;
  const float* ap = X + (size_t)(r0 + lm) * kV + chunk * 2048 + lg * 8;
  const __bf16* bp = Bp + ((size_t)(chunk * 64) * kNB + lm) * 32 + lg * 8;
  f32x4 acc[5] = {};
  #pragma unroll 4
  for (int s = 0; s < nsteps; ++s) {
    f4 x0 = *(const f4*)(ap + s * 32);
    f4 x1 = *(const f4*)(ap + s * 32 + 4);
    bf16x8 af = cvt8(x0, x1);
    const __bf16* bs = bp + (size_t)s * (kNB * 32);
    acc[0] = MFMA16(af, *(const bf16x8*)(bs + (f0 + 0) * 512), acc[0], 0, 0, 0);
    acc[1] = MFMA16(af, *(const bf16x8*)(bs + (f0 + 1) * 512), acc[1], 0, 0, 0);
    acc[2] = MFMA16(af, *(const bf16x8*)(bs + (f0 + 2) * 512), acc[2], 0, 0, 0);
    acc[3] = MFMA16(af, *(const bf16x8*)(bs + (f0 + 3) * 512), acc[3], 0, 0, 0);
    if (w == 3)
      acc[4] = MFMA16(af, *(const bf16x8*)(bs + 16 * 512), acc[4], 0, 0, 0);
  }
  if (lastc) {  // panel 312: k 9984..10016 (Bp zero-padded past 10000)
    f4 z = make_float4(0.f, 0.f, 0.f, 0.f), x0 = z, x1 = z;
    if (lg < 2) {
      x0 = *(const f4*)(ap + 56 * 32);
      x1 = *(const f4*)(ap + 56 * 32 + 4);
    }
    bf16x8 af = cvt8(x0, x1);
    const __bf16* bs = bp + (size_t)56 * (kNB * 32);
    acc[0] = MFMA16(af, *(const bf16x8*)(bs + (f0 + 0) * 512), acc[0], 0, 0, 0);
    acc[1] = MFMA16(af, *(const bf16x8*)(bs + (f0 + 1) * 512), acc[1], 0, 0, 0);
    acc[2] = MFMA16(af, *(const bf16x8*)(bs + (f0 + 2) * 512), acc[2], 0, 0, 0);
    acc[3] = MFMA16(af, *(const bf16x8*)(bs + (f0 + 3) * 512), acc[3], 0, 0, 0);
    if (w == 3)
      acc[4] = MFMA16(af, *(const bf16x8*)(bs + 16 * 512), acc[4], 0, 0, 0);
  }
  #pragma unroll
  for (int j = 0; j < 4; ++j) {
    int r = r0 + lg * 4 + j;                 // memory row
    int bt = (r & 63) * kT + (r >> 6);       // -> bt index
    size_t o = ((size_t)chunk * kBT + bt) * kNB;
    #pragma unroll
    for (int f = 0; f < 4; ++f) part[o + (f0 + f) * 16 + lm] = acc[f][j];
    if (w == 3) part[o + 256 + lm] = acc[4][j];
  }
}

// ----- creduce: sum 5 chunk-partials -> ontoV / pwred / pc / sp -------------
__global__ __launch_bounds__(256) void mmore_creduce(
    const float* __restrict__ part, float* __restrict__ ontoV,
    float* __restrict__ pwred, float* __restrict__ pc, float* __restrict__ sp) {
  int bt = blockIdx.x, t = threadIdx.x;
  for (int c = t; c < kNB; c += 256) {
    float a = 0.f;
    #pragma unroll
    for (int ch = 0; ch < kXC; ++ch)
      a += part[((size_t)ch * kBT + bt) * kNB + c];
    if (c < 128) ontoV[(size_t)bt * 128 + c] = a;
    else if (c < 256) pwred[(size_t)bt * 128 + (c - 128)] = a;
    else if (c == 256) pc[bt] = a;
    else if (c == 257) sp[bt] = a;
  }
}

// ----- loss GEMM: epart[vt][bt] = sum_{c in vtile} e^(ehrV@coW + cob) -------
__global__ __launch_bounds__(256) void mmore_lossg(
    const float* __restrict__ ehrV, const __bf16* __restrict__ coWT,
    const float* __restrict__ cob, float* __restrict__ epart) {
  int t = threadIdx.x, wave = t >> 6, lane = t & 63, lm = lane & 15, lg = lane >> 4;
  int vt = blockIdx.x, btile = blockIdx.y;
  int r0 = btile * 32, vb = vt * 256;
  const float* a0 = ehrV + (size_t)(r0 + lm) * 128 + lg * 8;
  const float* a1 = a0 + 16 * 128;
  f32x4 acc[2][4] = {};
  #pragma unroll
  for (int kb = 0; kb < 128; kb += 32) {
    f4 x0 = *(const f4*)(a0 + kb), x1 = *(const f4*)(a0 + kb + 4);
    f4 y0 = *(const f4*)(a1 + kb), y1 = *(const f4*)(a1 + kb + 4);
    bf16x8 af0 = cvt8(x0, x1), af1 = cvt8(y0, y1);
    #pragma unroll
    for (int nf = 0; nf < 4; ++nf) {
      int c = vb + wave * 64 + nf * 16 + lm;
      bf16x8 b = *(const bf16x8*)(coWT + (size_t)c * 128 + kb + lg * 8);
      acc[0][nf] = MFMA16(af0, b, acc[0][nf], 0, 0, 0);
      acc[1][nf] = MFMA16(af1, b, acc[1][nf], 0, 0, 0);
    }
  }
  float se[2][4] = {};
  #pragma unroll
  for (int nf = 0; nf < 4; ++nf) {
    int c = vb + wave * 64 + nf * 16 + lm;
    if (c < kV) {
      float cb = cob[c];
      #pragma unroll
      for (int mf = 0; mf < 2; ++mf)
        #pragma unroll
        for (int j = 0; j < 4; ++j)
          se[mf][j] += __expf(acc[mf][nf][j] + cb);
    }
  }
  __shared__ float red[4][32];
  #pragma unroll
  for (int mf = 0; mf < 2; ++mf)
    #pragma unroll
    for (int j = 0; j < 4; ++j) {
      float v = se[mf][j];
      #pragma unroll
      for (int off = 8; off; off >>= 1) v += __shfl_xor(v, off);
      if (lm == 0) red[wave][mf * 16 + lg * 4 + j] = v;
    }
  __syncthreads();
  if (t < 32)
    epart[(size_t)vt * kBT + r0 + t] =
        red[0][t] + red[1][t] + red[2][t] + red[3][t];
}

// ----- lossterm: term[bt] = (ehrV.pwred + pc) - sp*log(sum epart) -----------
__global__ __launch_bounds__(256) void mmore_lossterm(
    const float* __restrict__ ehrV, const float* __restrict__ pwred,
    const float* __restrict__ pc, const float* __restrict__ sp,
    const float* __restrict__ epart, float* __restrict__ term) {
  int t = threadIdx.x;
  int bt = blockIdx.x * 16 + (t >> 4);
  int sub = t & 15;
  const f4* e = (const f4*)(ehrV + (size_t)bt * 128 + sub * 8);
  const f4* w = (const f4*)(pwred + (size_t)bt * 128 + sub * 8);
  f4 e0 = e[0], e1 = e[1], w0 = w[0], w1 = w[1];
  float d = e0.x * w0.x + e0.y * w0.y + e0.z * w0.z + e0.w * w0.w +
            e1.x * w1.x + e1.y * w1.y + e1.z * w1.z + e1.w * w1.w;
  float S = 0.f;
  for (int vt = sub; vt < kVT2; vt += 16) S += epart[(size_t)vt * kBT + bt];
  #pragma unroll
  for (int off = 8; off; off >>= 1) {
    d += __shfl_xor(d, off); S += __shfl_xor(S, off);
  }
  if (sub == 0) term[bt] = (d + pc[bt]) - sp[bt] * logf(S);
}

__global__ __launch_bounds__(256) void mmore_lossfin(
    const float* __restrict__ term, float* __restrict__ out) {
  int t = threadIdx.x;
  float a = 0.f;
  for (int i = t; i < kBT; i += 256) a += term[i];
  #pragma unroll
  for (int off = 32; off; off >>= 1) a += __shfl_down(a, off);
  __shared__ float red[4];
  if ((t & 63) == 0) red[t >> 6] = a;
  __syncthreads();
  if (t == 0) out[0] = -(10.f / 64.f) * (red[0] + red[1] + red[2] + red[3]);
}

// ---------------- generic MFMA: C[M][128] (+=) A[M][128] @ WT[n][ldWT]+koff --
__global__ __launch_bounds__(256) void mmore_gemm_mfma(
    const float* __restrict__ A, const __bf16* __restrict__ WT,
    int ldWT, int koff, const float* __restrict__ bias,
    float* __restrict__ C, int M, int accumulate) {
  int t = threadIdx.x, wave = t >> 6, lane = t & 63, lm = lane & 15, lg = lane >> 4;
  int r0 = blockIdx.x * 32;
  int row0 = r0 + lm, row1 = row0 + 16;
  bool ok0 = row0 < M, ok1 = row1 < M;
  const float* a0 = A + (size_t)row0 * 128 + lg * 8;
  const float* a1 = A + (size_t)row1 * 128 + lg * 8;
  const __bf16* bp = WT + (size_t)(wave * 32 + lm) * ldWT + koff + lg * 8;
  int ld16 = 16 * ldWT;
  f32x4 acc[2][2] = {};
  #pragma unroll
  for (int kb = 0; kb < 128; kb += 32) {
    f4 x0 = make_float4(0, 0, 0, 0), x1 = x0, y0 = x0, y1 = x0;
    if (ok0) { x0 = *(const f4*)(a0 + kb); x1 = *(const f4*)(a0 + kb + 4); }
    if (ok1) { y0 = *(const f4*)(a1 + kb); y1 = *(const f4*)(a1 + kb + 4); }
    bf16x8 af0 = cvt8(x0, x1), af1 = cvt8(y0, y1);
    bf16x8 b0 = *(const bf16x8*)(bp + kb);
    bf16x8 b1 = *(const bf16x8*)(bp + kb + ld16);
    acc[0][0] = MFMA16(af0, b0, acc[0][0], 0, 0, 0);
    acc[0][1] = MFMA16(af0, b1, acc[0][1], 0, 0, 0);
    acc[1][0] = MFMA16(af1, b0, acc[1][0], 0, 0, 0);
    acc[1][1] = MFMA16(af1, b1, acc[1][1], 0, 0, 0);
  }
  #pragma unroll
  for (int mf = 0; mf < 2; ++mf)
    #pragma unroll
    for (int nf = 0; nf < 2; ++nf) {
      int col = wave * 32 + nf * 16 + lm;
      #pragma unroll
      for (int j = 0; j < 4; ++j) {
        int row = r0 + mf * 16 + lg * 4 + j;
        if (row < M) {
          float v = acc[mf][nf][j];
          if (bias) v += bias[col];
          if (accumulate) v += C[(size_t)row * 128 + col];
          C[(size_t)row * 128 + col] = v;
        }
      }
    }
}

// ---------------- per-(b,t): Bahdanau attention -> tn = tanh(l2norm(vs2)) ----
__device__ __forceinline__ float mmore_block_sum(float v, float* red) {
  int t = threadIdx.x;
  #pragma unroll
  for (int off = 32; off; off >>= 1) v += __shfl_down(v, off);
  if ((t & 63) == 0) red[t >> 6] = v;
  __syncthreads();
  if (t == 0) red[0] = red[0] + red[1] + red[2] + red[3];
  __syncthreads();
  return red[0];
}

__global__ __launch_bounds__(256) void mmore_attn(
    const int* __restrict__ dxseqs, const float* __restrict__ base,
    const float* __restrict__ pe, const float* __restrict__ po,
    const float* __restrict__ combW, const float* __restrict__ combB,
    const float* __restrict__ ehr_table, const float* __restrict__ onto_all,
    float* __restrict__ tn) {
  __shared__ float base_s[128];
  __shared__ int idx_s[kN];
  __shared__ float scp[kN][2];
  __shared__ float attn_s[64];
  __shared__ float red[4];
  int bt = blockIdx.x, t = threadIdx.x;
  if (t < 128) base_s[t] = base[bt * 128 + t];
  if (t < kN) idx_s[t] = dxseqs[bt * kN + t];
  __syncthreads();
  int c = t & 127, half = t >> 7, wid = t >> 6, lane = t & 63;
  float cw = combW[c];
  for (int n2 = 0; n2 < kN / 2; ++n2) {
    int n = n2 * 2 + half;
    int id = idx_s[n];
    float x = base_s[c] + pe[(size_t)id * 128 + c] + po[(size_t)id * 128 + c];
    float val = tanhf(x) * cw;
    #pragma unroll
    for (int off = 32; off; off >>= 1) val += __shfl_down(val, off);
    if (lane == 0) scp[n][wid & 1] = val;
  }
  __syncthreads();
  if (t < 64) {
    float s = (t < kN) ? (scp[t][0] + scp[t][1] + combB[0]) : -1e30f;
    float mx = s;
    #pragma unroll
    for (int off = 32; off; off >>= 1) mx = fmaxf(mx, __shfl_xor(mx, off));
    float e = (t < kN) ? __expf(s - mx) : 0.f;
    float sm = e;
    #pragma unroll
    for (int off = 32; off; off >>= 1) sm += __shfl_xor(sm, off);
    attn_s[t] = e / sm;
  }
  __syncthreads();
  float acc = 0.f;
  {
    const float* tab = (t < 128) ? ehr_table : onto_all;
    int j = t & 127;
    for (int n = 0; n < kN; ++n)
      acc += attn_s[n] * tab[(size_t)idx_s[n] * 128 + j];
  }
  float ss = mmore_block_sum(acc * acc, red);
  float inv = 1.f / fmaxf(sqrtf(ss), 1e-12f);
  tn[(size_t)bt * 256 + t] = tanhf(acc * inv);
}

// ---------------- dp head GEMM: u[2048][512] = tn@dpWT + dpB ----------------
__global__ __launch_bounds__(256) void mmore_dpgemm(
    const float* __restrict__ tn, const __bf16* __restrict__ dpWT,
    const float* __restrict__ dpB, float* __restrict__ u) {
  int t = threadIdx.x, wave = t >> 6, lane = t & 63, lm = lane & 15, lg = lane >> 4;
  int c0 = blockIdx.x * 128, r0 = blockIdx.y * 32;
  const float* a0 = tn + (size_t)(r0 + lm) * 256 + lg * 8;
  const float* a1 = a0 + 16 * 256;
  const __bf16* bp = dpWT + (size_t)(c0 + wave * 32 + lm) * 256 + lg * 8;
  f32x4 acc[2][2] = {};
  #pragma unroll
  for (int kb = 0; kb < 256; kb += 32) {
    f4 x0 = *(const f4*)(a0 + kb), x1 = *(const f4*)(a0 + kb + 4);
    f4 y0 = *(const f4*)(a1 + kb), y1 = *(const f4*)(a1 + kb + 4);
    bf16x8 af0 = cvt8(x0, x1), af1 = cvt8(y0, y1);
    bf16x8 b0 = *(const bf16x8*)(bp + kb);
    bf16x8 b1 = *(const bf16x8*)(bp + kb + 16 * 256);
    acc[0][0] = MFMA16(af0, b0, acc[0][0], 0, 0, 0);
    acc[0][1] = MFMA16(af0, b1, acc[0][1], 0, 0, 0);
    acc[1][0] = MFMA16(af1, b0, acc[1][0], 0, 0, 0);
    acc[1][1] = MFMA16(af1, b1, acc[1][1], 0, 0, 0);
  }
  #pragma unroll
  for (int mf = 0; mf < 2; ++mf)
    #pragma unroll
    for (int nf = 0; nf < 2; ++nf) {
      int col = c0 + wave * 32 + nf * 16 + lm;
      float bias = (col < kDPL) ? dpB[col] : 0.f;
      #pragma unroll
      for (int j = 0; j < 4; ++j) {
        int row = r0 + mf * 16 + lg * 4 + j;
        u[(size_t)row * 512 + col] = acc[mf][nf][j] + bias;
      }
    }
}

// ---------------- dp softmax over 500 cols ----------------
__global__ __launch_bounds__(128) void mmore_dpsoft(
    const float* __restrict__ u, float* __restrict__ out) {
  int bt = blockIdx.x, t = threadIdx.x;
  __shared__ float red[2];
  float v[4]; float mx = -1e30f;
  #pragma unroll
  for (int i = 0; i < 4; ++i) {
    int c = t + i * 128;
    v[i] = (c < kDPL) ? u[(size_t)bt * 512 + c] : -1e30f;
    mx = fmaxf(mx, v[i]);
  }
  #pragma unroll
  for (int off = 32; off; off >>= 1) mx = fmaxf(mx, __shfl_xor(mx, off));
  if ((t & 63) == 0) red[t >> 6] = mx;
  __syncthreads();
  mx = fmaxf(red[0], red[1]);
  __syncthreads();
  float e[4], s = 0.f;
  #pragma unroll
  for (int i = 0; i < 4; ++i) {
    int c = t + i * 128;
    e[i] = (c < kDPL) ? __expf(v[i] - mx) : 0.f;
    s += e[i];
  }
  #pragma unroll
  for (int off = 32; off; off >>= 1) s += __shfl_xor(s, off);
  if ((t & 63) == 0) red[t >> 6] = s;
  __syncthreads();
  float invS = 1.f / (red[0] + red[1]);
  #pragma unroll
  for (int i = 0; i < 4; ++i) {
    int c = t + i * 128;
    if (c < kDPL) out[(size_t)bt * kDPL + c] = e[i] * invS;
  }
}

extern "C" void kernel_launch(void* const* d_in, const int* in_sizes, int n_in,
                              void* d_out, int out_size, void* d_ws, size_t ws_size,
                              hipStream_t stream) {
  const int*   dxseqs     = (const int*)d_in[0];
  const float* dx_onehot  = (const float*)d_in[1];
  const int*   leaves     = (const int*)d_in[2];
  const int*   ancestors  = (const int*)d_in[3];
  const float* onto_table = (const float*)d_in[4];
  const float* onto_Wa    = (const float*)d_in[5];
  const float* onto_ba    = (const float*)d_in[6];
  const float* onto_Wc    = (const float*)d_in[7];
  const float* onto_bc    = (const float*)d_in[8];
  const float* ehr_table  = (const float*)d_in[9];
  const float* attn_W     = (const float*)d_in[10];
  const float* attn_b     = (const float*)d_in[11];
  const float* comb_W     = (const float*)d_in[12];
  const float* comb_b     = (const float*)d_in[13];
  const float* co_W       = (const float*)d_in[14];
  const float* co_b       = (const float*)d_in[15];
  const float* dp_W       = (const float*)d_in[16];
  const float* dp_b       = (const float*)d_in[17];
  float* out = (float*)d_out;

  // ---- workspace (~26.2 MB) ----
  float* ws = (float*)d_ws;
  size_t off = 0;
  auto alloc = [&](size_t n) { float* p = ws + off; off += n; return p; };
  float* onto_all = alloc((size_t)(kV + 1) * 128);             // 1,280,128
  float* s_sc     = alloc((size_t)kV * kL);                    //    60,000
  float* ehrV     = alloc((size_t)kBT * 128);                  //   262,144
  float* ontoV    = alloc((size_t)kBT * 128);                  //   262,144
  __bf16* Bp      = (__bf16*)alloc((size_t)kNP * kNB * 32 / 2);// 1,362,176 fl
  __bf16* attn_WT = (__bf16*)alloc((size_t)128 * 512 / 2);     //    32,768 fl
  __bf16* dpWT    = (__bf16*)alloc((size_t)512 * 256 / 2);     //    65,536 fl
  __bf16* WaT     = (__bf16*)alloc((size_t)128 * 256 / 2);     //    16,384 fl
  float* peR      = alloc((size_t)(kV + 1) * 128);             // 1,280,128
  float* poR      = alloc((size_t)(kV + 1) * 128);             // 1,280,128
  float* basep    = alloc((size_t)kBT * 128);                  //   262,144
  float* epart    = alloc((size_t)kVT2 * kBT);                 //    81,920
  float* pwred    = alloc((size_t)kBT * 128);                  //   262,144
  float* pc       = alloc(kBT);                                //     2,048
  float* sp       = alloc(kBT);                                //     2,048
  float* term     = alloc(kBT);                                //     2,048
  // time-disjoint aliases in the peR..basep span (2,822,400 fl):
  __bf16* ot_bf = (__bf16*)peR;  // scores input; dead before Btab build
  __bf16* BtabL = (__bf16*)peR;  // linear Btab (1,392,640 fl); built after
                                 // scores, dead after panelize
  float*  cpart = peR;           // xgemm partials (2,785,280 fl); overwrites
                                 // BtabL, dead after creduce
  __bf16* coWT  = (__bf16*)peR;  // loss B (655,360 fl); built after creduce,
                                 // dead before pe-gemm writes peR
  float*  u     = peR;           // dp logits; written after attn reads peR
  float*  tn    = ehrV;          // attn out; written after last ehrV/ontoV reads

  // ---- prep ----
  mmore_cvt_bf16<<<663, 256, 0, stream>>>(onto_table, ot_bf, 10600 * 128);
  mmore_trcvt<<<dim3(2, 8), 256, 0, stream>>>(onto_Wa, WaT, 256, 128, 256);
  mmore_trcvt<<<dim3(4, 8), 256, 0, stream>>>(attn_W, attn_WT, 512, 128, 512);
  mmore_trcvt<<<dim3(2, 32), 256, 0, stream>>>(dp_W, dpWT, 256, kDPL, 256);

  mmore_ehrv<<<kBT, 128, 0, stream>>>(dxseqs, ehr_table, ehrV);
  mmore_scores_mfma<<<(kV * kL) / 32, 256, 0, stream>>>(
      ot_bf, leaves, ancestors, WaT, onto_ba, onto_Wc, onto_bc, s_sc);
  mmore_onto<<<kV + 1, 128, 0, stream>>>(onto_table, ancestors, s_sc, onto_all);
  // Btab (linear) in peR-span (ot_bf dead), then panelize -> Bp
  mmore_trcvt<<<dim3(80, 8), 256, 0, stream>>>(onto_all, BtabL, kV, 128, kLd);
  mmore_brow<<<720, 256, 0, stream>>>(co_W, co_b, BtabL);
  mmore_panelize<<<dim3(kNP, 17), 256, 0, stream>>>(BtabL, Bp);
  mmore_xgemm<<<128 * kXC, 256, 0, stream>>>(dx_onehot, Bp, cpart);
  mmore_creduce<<<kBT, 256, 0, stream>>>(cpart, ontoV, pwred, pc, sp);
  mmore_trcvt<<<dim3(1, 640), 256, 0, stream>>>(co_W, coWT, 128, kV, 128);
  mmore_lossg<<<dim3(kVT2, 64), 256, 0, stream>>>(ehrV, coWT, co_b, epart);
  mmore_lossterm<<<kBT / 16, 256, 0, stream>>>(ehrV, pwred, pc, sp, epart, term);
  mmore_lossfin<<<1, 256, 0, stream>>>(term, out + (size_t)kBT * kDPL);
  mmore_gemm_mfma<<<313, 256, 0, stream>>>(ehr_table, attn_WT, 512, 256, nullptr, peR, kV + 1, 0);
  mmore_gemm_mfma<<<313, 256, 0, stream>>>(onto_all, attn_WT, 512, 384, nullptr, poR, kV + 1, 0);
  mmore_gemm_mfma<<<64, 256, 0, stream>>>(ontoV, attn_WT, 512, 0, nullptr, basep, kBT, 0);
  mmore_gemm_mfma<<<64, 256, 0, stream>>>(ehrV, attn_WT, 512, 128, attn_b, basep, kBT, 1);
  mmore_attn<<<kBT, 256, 0, stream>>>(dxseqs, basep, peR, poR, comb_W, comb_b,
                                      ehr_table, onto_all, tn);
  mmore_dpgemm<<<dim3(4, 64), 256, 0, stream>>>(tn, dpWT, dp_b, u);
  mmore_dpsoft<<<kBT, 128, 0, stream>>>(u, out);
}

// Round 9
// 303.991 us; speedup vs baseline: 1.1746x; 1.0019x over previous
//
#include <hip/hip_runtime.h>
#include <math.h>

typedef float4 f4;
typedef __bf16 bf16x8 __attribute__((ext_vector_type(8)));
typedef float f32x4 __attribute__((ext_vector_type(4)));

static constexpr int kV = 10000, kL = 6, kDPL = 500;
static constexpr int kB = 64, kT = 32, kN = 40, kBT = 2048;
static constexpr int kXC = 5;          // xgemm K-chunks (4 x 2048 + 1824)
static constexpr int kNB = 272;        // xgemm out cols (258 useful)
static constexpr int kLd = 10240;      // Btab/coWT k-/n- pad
static constexpr int kNP = 313;        // panels (10016 k padded)
static constexpr int kVT2 = 40;        // loss v-tiles of 256

#define MFMA16 __builtin_amdgcn_mfma_f32_16x16x32_bf16

__device__ __forceinline__ bf16x8 cvt8(f4 a, f4 b) {
  bf16x8 r;
  r[0] = (__bf16)a.x; r[1] = (__bf16)a.y; r[2] = (__bf16)a.z; r[3] = (__bf16)a.w;
  r[4] = (__bf16)b.x; r[5] = (__bf16)b.y; r[6] = (__bf16)b.z; r[7] = (__bf16)b.w;
  return r;
}

// ---------------- fp32 -> bf16 elementwise ----------------
__global__ __launch_bounds__(256) void mmore_cvt_bf16(
    const float* __restrict__ in, __bf16* __restrict__ out, int n) {
  int i = (blockIdx.x * 256 + threadIdx.x) * 8;
  if (i < n) {
    f4 a = *(const f4*)(in + i), b = *(const f4*)(in + i + 4);
    *(bf16x8*)(out + i) = cvt8(a, b);
  }
}

// -------- transpose+cvt: out[n][k] (bf16, k/n-pad zeros) = in[k][n] ---------
__global__ __launch_bounds__(256) void mmore_trcvt(
    const float* __restrict__ in, __bf16* __restrict__ out,
    int K, int N, int Kpad) {
  int t = threadIdx.x;
  int n = blockIdx.y * 16 + (t & 15);
  int kb = (blockIdx.x * 16 + (t >> 4)) * 8;
  bf16x8 r;
  #pragma unroll
  for (int i = 0; i < 8; ++i) {
    int k = kb + i;
    float v = (k < K && n < N) ? in[(size_t)k * N + n] : 0.f;
    r[i] = (__bf16)v;
  }
  *(bf16x8*)(out + (size_t)n * Kpad + kb) = r;
}

// -------- Btab rows 128..271: coW rows (k-contig), cob, ones, zeros ---------
__global__ __launch_bounds__(256) void mmore_brow(
    const float* __restrict__ coW, const float* __restrict__ cob,
    __bf16* __restrict__ Btab) {
  int id = blockIdx.x * 256 + threadIdx.x;
  int rr = id / 1280;               // 0..143
  int kk = (id - rr * 1280) * 8;
  bf16x8 r;
  #pragma unroll
  for (int i = 0; i < 8; ++i) {
    int k = kk + i;
    float v = 0.f;
    if (k < kV) {
      if (rr < 128) v = coW[(size_t)rr * kV + k];
      else if (rr == 128) v = cob[k];
      else if (rr == 129) v = 1.f;
    }
    r[i] = (__bf16)v;
  }
  *(bf16x8*)(Btab + (size_t)(128 + rr) * kLd + kk) = r;
}

// -------- panelize: Bp[S][272][32] = Btab[row][S*32+kk] ---------------------
__global__ __launch_bounds__(256) void mmore_panelize(
    const __bf16* __restrict__ Btab, __bf16* __restrict__ Bp) {
  int t = threadIdx.x;
  int S = blockIdx.x, ry = blockIdx.y;
  int row = ry * 16 + (t >> 4), kk = (t & 15) * 2;
  unsigned v = *(const unsigned*)(Btab + (size_t)row * kLd + S * 32 + kk);
  *(unsigned*)(Bp + ((size_t)S * kNB + row) * 32 + kk) = v;
}

// ---------------- ehrV = l2norm(sum_n ehr_table[dxseqs]) ----------------
__global__ __launch_bounds__(128) void mmore_ehrv(
    const int* __restrict__ dxseqs, const float* __restrict__ ehr_table,
    float* __restrict__ ehrV) {
  int bt = blockIdx.x, t = threadIdx.x;
  const int* row = dxseqs + bt * kN;
  float acc = 0.f;
  for (int n = 0; n < kN; ++n) acc += ehr_table[(size_t)row[n] * 128 + t];
  float v = acc * acc;
  #pragma unroll
  for (int off = 32; off; off >>= 1) v += __shfl_down(v, off);
  __shared__ float red[2];
  if ((t & 63) == 0) red[t >> 6] = v;
  __syncthreads();
  float ss = red[0] + red[1];
  float inv = 1.f / fmaxf(sqrtf(ss), 1e-12f);
  ehrV[bt * 128 + t] = acc * inv;
}

// ---------------- GRAM scores via MFMA ----------------
__global__ __launch_bounds__(256) void mmore_scores_mfma(
    const __bf16* __restrict__ otb, const int* __restrict__ leaves,
    const int* __restrict__ anc, const __bf16* __restrict__ WaT,
    const float* __restrict__ ba, const float* __restrict__ Wc,
    const float* __restrict__ bc, float* __restrict__ s_out) {
  int t = threadIdx.x, wave = t >> 6, lane = t & 63, lm = lane & 15, lg = lane >> 4;
  int r0 = blockIdx.x * 32;
  int rA0 = r0 + lm, rA1 = rA0 + 16;
  int v0 = rA0 / 6, l0 = rA0 - v0 * 6, v1 = rA1 / 6, l1 = rA1 - v1 * 6;
  const __bf16* pL0 = otb + (size_t)leaves[v0 * 6 + l0] * 128;
  const __bf16* pA0 = otb + (size_t)anc[v0 * 6 + l0] * 128;
  const __bf16* pL1 = otb + (size_t)leaves[v1 * 6 + l1] * 128;
  const __bf16* pA1 = otb + (size_t)anc[v1 * 6 + l1] * 128;
  const __bf16* bp = WaT + (size_t)(wave * 32 + lm) * 256 + lg * 8;
  f32x4 acc[2][2] = {};
  #pragma unroll
  for (int kb = 0; kb < 256; kb += 32) {
    int k = kb + lg * 8;
    const __bf16* s0 = (k < 128) ? (pL0 + k) : (pA0 + (k - 128));
    const __bf16* s1 = (k < 128) ? (pL1 + k) : (pA1 + (k - 128));
    bf16x8 a0 = *(const bf16x8*)s0;
    bf16x8 a1 = *(const bf16x8*)s1;
    bf16x8 b0 = *(const bf16x8*)(bp + kb);
    bf16x8 b1 = *(const bf16x8*)(bp + kb + 16 * 256);
    acc[0][0] = MFMA16(a0, b0, acc[0][0], 0, 0, 0);
    acc[0][1] = MFMA16(a0, b1, acc[0][1], 0, 0, 0);
    acc[1][0] = MFMA16(a1, b0, acc[1][0], 0, 0, 0);
    acc[1][1] = MFMA16(a1, b1, acc[1][1], 0, 0, 0);
  }
  __shared__ float red[4][32];
  float bcv = bc[0];
  #pragma unroll
  for (int mf = 0; mf < 2; ++mf) {
    #pragma unroll
    for (int j = 0; j < 4; ++j) {
      float p = 0.f;
      #pragma unroll
      for (int nf = 0; nf < 2; ++nf) {
        int c = wave * 32 + nf * 16 + lm;
        p += tanhf(acc[mf][nf][j] + ba[c]) * Wc[c];
      }
      #pragma unroll
      for (int off = 8; off; off >>= 1) p += __shfl_xor(p, off);
      if (lm == 0) red[wave][mf * 16 + lg * 4 + j] = p;
    }
  }
  __syncthreads();
  if (t < 32) s_out[r0 + t] = red[0][t] + red[1][t] + red[2][t] + red[3][t] + bcv;
}

// ---------------- onto_all[v] = softmax_l(s) . ea ; row V = 0 ----------------
__global__ __launch_bounds__(128) void mmore_onto(
    const float* __restrict__ ot, const int* __restrict__ anc,
    const float* __restrict__ s_in, float* __restrict__ onto_all) {
  int v = blockIdx.x, t = threadIdx.x;
  if (v == kV) { onto_all[(size_t)v * 128 + t] = 0.f; return; }
  __shared__ float sv[kL];
  __shared__ int aidx[kL];
  if (t < kL) { sv[t] = s_in[v * kL + t]; aidx[t] = anc[v * kL + t]; }
  __syncthreads();
  float mx = sv[0];
  #pragma unroll
  for (int l = 1; l < kL; ++l) mx = fmaxf(mx, sv[l]);
  float e[kL], sum = 0.f;
  #pragma unroll
  for (int l = 0; l < kL; ++l) { e[l] = expf(sv[l] - mx); sum += e[l]; }
  float acc = 0.f;
  #pragma unroll
  for (int l = 0; l < kL; ++l)
    acc += (e[l] / sum) * ot[(size_t)aidx[l] * 128 + t];
  onto_all[(size_t)v * 128 + t] = acc;
}

// ===== fused X-GEMM v4: part[chunk][bt][272] = X @ Bp (panelized B) =========
// Direct-load streamer, NO LDS / NO barriers, with EXPLICIT ping-pong A
// prefetch: group = 4 K-steps = 8xf4/lane (32 VGPR), next group's loads issue
// before current group's MFMA -> ~8KB/wave continuously in flight.
// BM=16, 4 waves (wave w owns col-frags w*4..w*4+3, +frag 16 on wave 3).
// Grid 128 btiles x 5 chunks = 640 blocks, XCD-swizzled (640%8==0).
#define XG_LOADA(dst, g)                                                      \
  {                                                                           \
    const float* ap_ = ap + (size_t)(g) * 128;                                \
    _Pragma("unroll")                                                         \
    for (int j = 0; j < 4; ++j) {                                             \
      dst##0[j] = *(const f4*)(ap_ + j * 32);                                 \
      dst##1[j] = *(const f4*)(ap_ + j * 32 + 4);                             \
    }                                                                         \
  }

#define XG_COMPG(src, g)                                                      \
  {                                                                           \
    _Pragma("unroll")                                                         \
    for (int j = 0; j < 4; ++j) {                                             \
      bf16x8 af_ = cvt8(src##0[j], src##1[j]);                                \
      const __bf16* bs_ = bp + (size_t)((g) * 4 + j) * (kNB * 32);            \
      acc[0] = MFMA16(af_, *(const bf16x8*)(bs_ + (f0 + 0) * 512), acc[0], 0, 0, 0); \
      acc[1] = MFMA16(af_, *(const bf16x8*)(bs_ + (f0 + 1) * 512), acc[1], 0, 0, 0); \
      acc[2] = MFMA16(af_, *(const bf16x8*)(bs_ + (f0 + 2) * 512), acc[2], 0, 0, 0); \
      acc[3] = MFMA16(af_, *(const bf16x8*)(bs_ + (f0 + 3) * 512), acc[3], 0, 0, 0); \
      if (w == 3)                                                             \
        acc[4] = MFMA16(af_, *(const bf16x8*)(bs_ + 16 * 512), acc[4], 0, 0, 0); \
    }                                                                         \
  }

__global__ __launch_bounds__(256) void mmore_xgemm(
    const float* __restrict__ X, const __bf16* __restrict__ Bp,
    float* __restrict__ part) {
  int t = threadIdx.x, w = t >> 6, lane = t & 63, lm = lane & 15, lg = lane >> 4;
  int bid = blockIdx.x;
  int swz = (bid & 7) * 80 + (bid >> 3);     // bijective XCD swizzle
  int btile = swz & 127, chunk = swz >> 7;
  int r0 = btile * 16;
  bool lastc = (chunk == kXC - 1);
  int nG = lastc ? 14 : 16;                  // groups of 4 steps (128 k)
  int f0 = w * 4;
  const float* ap = X + (size_t)(r0 + lm) * kV + chunk * 2048 + lg * 8;
  const __bf16* bp = Bp + ((size_t)(chunk * 64) * kNB + lm) * 32 + lg * 8;
  f32x4 acc[5] = {};
  f4 aP0[4], aP1[4], aQ0[4], aQ1[4];

  XG_LOADA(aP, 0);
  int g = 0;
  for (; g + 2 < nG; g += 2) {
    XG_LOADA(aQ, g + 1);
    XG_COMPG(aP, g);
    XG_LOADA(aP, g + 2);
    XG_COMPG(aQ, g + 1);
  }
  XG_LOADA(aQ, g + 1);   // nG even: g == nG-2 here
  XG_COMPG(aP, g);
  XG_COMPG(aQ, g + 1);

  if (lastc) {  // panel 312: k 9984..10016 (Bp zero-padded past 10000)
    f4 z = make_float4(0.f, 0.f, 0.f, 0.f), x0 = z, x1 = z;
    if (lg < 2) {
      x0 = *(const f4*)(ap + 56 * 32);
      x1 = *(const f4*)(ap + 56 * 32 + 4);
    }
    bf16x8 af = cvt8(x0, x1);
    const __bf16* bs = bp + (size_t)56 * (kNB * 32);
    acc[0] = MFMA16(af, *(const bf16x8*)(bs + (f0 + 0) * 512), acc[0], 0, 0, 0);
    acc[1] = MFMA16(af, *(const bf16x8*)(bs + (f0 + 1) * 512), acc[1], 0, 0, 0);
    acc[2] = MFMA16(af, *(const bf16x8*)(bs + (f0 + 2) * 512), acc[2], 0, 0, 0);
    acc[3] = MFMA16(af, *(const bf16x8*)(bs + (f0 + 3) * 512), acc[3], 0, 0, 0);
    if (w == 3)
      acc[4] = MFMA16(af, *(const bf16x8*)(bs + 16 * 512), acc[4], 0, 0, 0);
  }
  #pragma unroll
  for (int j = 0; j < 4; ++j) {
    int r = r0 + lg * 4 + j;                 // memory row
    int bt = (r & 63) * kT + (r >> 6);       // -> bt index
    size_t o = ((size_t)chunk * kBT + bt) * kNB;
    #pragma unroll
    for (int f = 0; f < 4; ++f) part[o + (f0 + f) * 16 + lm] = acc[f][j];
    if (w == 3) part[o + 256 + lm] = acc[4][j];
  }
}

// ----- creduce: sum 5 chunk-partials -> ontoV / pwred / pc / sp -------------
__global__ __launch_bounds__(256) void mmore_creduce(
    const float* __restrict__ part, float* __restrict__ ontoV,
    float* __restrict__ pwred, float* __restrict__ pc, float* __restrict__ sp) {
  int bt = blockIdx.x, t = threadIdx.x;
  for (int c = t; c < kNB; c += 256) {
    float a = 0.f;
    #pragma unroll
    for (int ch = 0; ch < kXC; ++ch)
      a += part[((size_t)ch * kBT + bt) * kNB + c];
    if (c < 128) ontoV[(size_t)bt * 128 + c] = a;
    else if (c < 256) pwred[(size_t)bt * 128 + (c - 128)] = a;
    else if (c == 256) pc[bt] = a;
    else if (c == 257) sp[bt] = a;
  }
}

// ----- loss GEMM: epart[vt][bt] = sum_{c in vtile} e^(ehrV@coW + cob) -------
__global__ __launch_bounds__(256) void mmore_lossg(
    const float* __restrict__ ehrV, const __bf16* __restrict__ coWT,
    const float* __restrict__ cob, float* __restrict__ epart) {
  int t = threadIdx.x, wave = t >> 6, lane = t & 63, lm = lane & 15, lg = lane >> 4;
  int vt = blockIdx.x, btile = blockIdx.y;
  int r0 = btile * 32, vb = vt * 256;
  const float* a0 = ehrV + (size_t)(r0 + lm) * 128 + lg * 8;
  const float* a1 = a0 + 16 * 128;
  f32x4 acc[2][4] = {};
  #pragma unroll
  for (int kb = 0; kb < 128; kb += 32) {
    f4 x0 = *(const f4*)(a0 + kb), x1 = *(const f4*)(a0 + kb + 4);
    f4 y0 = *(const f4*)(a1 + kb), y1 = *(const f4*)(a1 + kb + 4);
    bf16x8 af0 = cvt8(x0, x1), af1 = cvt8(y0, y1);
    #pragma unroll
    for (int nf = 0; nf < 4; ++nf) {
      int c = vb + wave * 64 + nf * 16 + lm;
      bf16x8 b = *(const bf16x8*)(coWT + (size_t)c * 128 + kb + lg * 8);
      acc[0][nf] = MFMA16(af0, b, acc[0][nf], 0, 0, 0);
      acc[1][nf] = MFMA16(af1, b, acc[1][nf], 0, 0, 0);
    }
  }
  float se[2][4] = {};
  #pragma unroll
  for (int nf = 0; nf < 4; ++nf) {
    int c = vb + wave * 64 + nf * 16 + lm;
    if (c < kV) {
      float cb = cob[c];
      #pragma unroll
      for (int mf = 0; mf < 2; ++mf)
        #pragma unroll
        for (int j = 0; j < 4; ++j)
          se[mf][j] += __expf(acc[mf][nf][j] + cb);
    }
  }
  __shared__ float red[4][32];
  #pragma unroll
  for (int mf = 0; mf < 2; ++mf)
    #pragma unroll
    for (int j = 0; j < 4; ++j) {
      float v = se[mf][j];
      #pragma unroll
      for (int off = 8; off; off >>= 1) v += __shfl_xor(v, off);
      if (lm == 0) red[wave][mf * 16 + lg * 4 + j] = v;
    }
  __syncthreads();
  if (t < 32)
    epart[(size_t)vt * kBT + r0 + t] =
        red[0][t] + red[1][t] + red[2][t] + red[3][t];
}

// ----- lossterm: term[bt] = (ehrV.pwred + pc) - sp*log(sum epart) -----------
__global__ __launch_bounds__(256) void mmore_lossterm(
    const float* __restrict__ ehrV, const float* __restrict__ pwred,
    const float* __restrict__ pc, const float* __restrict__ sp,
    const float* __restrict__ epart, float* __restrict__ term) {
  int t = threadIdx.x;
  int bt = blockIdx.x * 16 + (t >> 4);
  int sub = t & 15;
  const f4* e = (const f4*)(ehrV + (size_t)bt * 128 + sub * 8);
  const f4* w = (const f4*)(pwred + (size_t)bt * 128 + sub * 8);
  f4 e0 = e[0], e1 = e[1], w0 = w[0], w1 = w[1];
  float d = e0.x * w0.x + e0.y * w0.y + e0.z * w0.z + e0.w * w0.w +
            e1.x * w1.x + e1.y * w1.y + e1.z * w1.z + e1.w * w1.w;
  float S = 0.f;
  for (int vt = sub; vt < kVT2; vt += 16) S += epart[(size_t)vt * kBT + bt];
  #pragma unroll
  for (int off = 8; off; off >>= 1) {
    d += __shfl_xor(d, off); S += __shfl_xor(S, off);
  }
  if (sub == 0) term[bt] = (d + pc[bt]) - sp[bt] * logf(S);
}

__global__ __launch_bounds__(256) void mmore_lossfin(
    const float* __restrict__ term, float* __restrict__ out) {
  int t = threadIdx.x;
  float a = 0.f;
  for (int i = t; i < kBT; i += 256) a += term[i];
  #pragma unroll
  for (int off = 32; off; off >>= 1) a += __shfl_down(a, off);
  __shared__ float red[4];
  if ((t & 63) == 0) red[t >> 6] = a;
  __syncthreads();
  if (t == 0) out[0] = -(10.f / 64.f) * (red[0] + red[1] + red[2] + red[3]);
}

// ---------------- generic MFMA: C[M][128] (+=) A[M][128] @ WT[n][ldWT]+koff --
__global__ __launch_bounds__(256) void mmore_gemm_mfma(
    const float* __restrict__ A, const __bf16* __restrict__ WT,
    int ldWT, int koff, const float* __restrict__ bias,
    float* __restrict__ C, int M, int accumulate) {
  int t = threadIdx.x, wave = t >> 6, lane = t & 63, lm = lane & 15, lg = lane >> 4;
  int r0 = blockIdx.x * 32;
  int row0 = r0 + lm, row1 = row0 + 16;
  bool ok0 = row0 < M, ok1 = row1 < M;
  const float* a0 = A + (size_t)row0 * 128 + lg * 8;
  const float* a1 = A + (size_t)row1 * 128 + lg * 8;
  const __bf16* bp = WT + (size_t)(wave * 32 + lm) * ldWT + koff + lg * 8;
  int ld16 = 16 * ldWT;
  f32x4 acc[2][2] = {};
  #pragma unroll
  for (int kb = 0; kb < 128; kb += 32) {
    f4 x0 = make_float4(0, 0, 0, 0), x1 = x0, y0 = x0, y1 = x0;
    if (ok0) { x0 = *(const f4*)(a0 + kb); x1 = *(const f4*)(a0 + kb + 4); }
    if (ok1) { y0 = *(const f4*)(a1 + kb); y1 = *(const f4*)(a1 + kb + 4); }
    bf16x8 af0 = cvt8(x0, x1), af1 = cvt8(y0, y1);
    bf16x8 b0 = *(const bf16x8*)(bp + kb);
    bf16x8 b1 = *(const bf16x8*)(bp + kb + ld16);
    acc[0][0] = MFMA16(af0, b0, acc[0][0], 0, 0, 0);
    acc[0][1] = MFMA16(af0, b1, acc[0][1], 0, 0, 0);
    acc[1][0] = MFMA16(af1, b0, acc[1][0], 0, 0, 0);
    acc[1][1] = MFMA16(af1, b1, acc[1][1], 0, 0, 0);
  }
  #pragma unroll
  for (int mf = 0; mf < 2; ++mf)
    #pragma unroll
    for (int nf = 0; nf < 2; ++nf) {
      int col = wave * 32 + nf * 16 + lm;
      #pragma unroll
      for (int j = 0; j < 4; ++j) {
        int row = r0 + mf * 16 + lg * 4 + j;
        if (row < M) {
          float v = acc[mf][nf][j];
          if (bias) v += bias[col];
          if (accumulate) v += C[(size_t)row * 128 + col];
          C[(size_t)row * 128 + col] = v;
        }
      }
    }
}

// ---------------- per-(b,t): Bahdanau attention -> tn = tanh(l2norm(vs2)) ----
__device__ __forceinline__ float mmore_block_sum(float v, float* red) {
  int t = threadIdx.x;
  #pragma unroll
  for (int off = 32; off; off >>= 1) v += __shfl_down(v, off);
  if ((t & 63) == 0) red[t >> 6] = v;
  __syncthreads();
  if (t == 0) red[0] = red[0] + red[1] + red[2] + red[3];
  __syncthreads();
  return red[0];
}

__global__ __launch_bounds__(256) void mmore_attn(
    const int* __restrict__ dxseqs, const float* __restrict__ base,
    const float* __restrict__ pe, const float* __restrict__ po,
    const float* __restrict__ combW, const float* __restrict__ combB,
    const float* __restrict__ ehr_table, const float* __restrict__ onto_all,
    float* __restrict__ tn) {
  __shared__ float base_s[128];
  __shared__ int idx_s[kN];
  __shared__ float scp[kN][2];
  __shared__ float attn_s[64];
  __shared__ float red[4];
  int bt = blockIdx.x, t = threadIdx.x;
  if (t < 128) base_s[t] = base[bt * 128 + t];
  if (t < kN) idx_s[t] = dxseqs[bt * kN + t];
  __syncthreads();
  int c = t & 127, half = t >> 7, wid = t >> 6, lane = t & 63;
  float cw = combW[c];
  for (int n2 = 0; n2 < kN / 2; ++n2) {
    int n = n2 * 2 + half;
    int id = idx_s[n];
    float x = base_s[c] + pe[(size_t)id * 128 + c] + po[(size_t)id * 128 + c];
    float val = tanhf(x) * cw;
    #pragma unroll
    for (int off = 32; off; off >>= 1) val += __shfl_down(val, off);
    if (lane == 0) scp[n][wid & 1] = val;
  }
  __syncthreads();
  if (t < 64) {
    float s = (t < kN) ? (scp[t][0] + scp[t][1] + combB[0]) : -1e30f;
    float mx = s;
    #pragma unroll
    for (int off = 32; off; off >>= 1) mx = fmaxf(mx, __shfl_xor(mx, off));
    float e = (t < kN) ? __expf(s - mx) : 0.f;
    float sm = e;
    #pragma unroll
    for (int off = 32; off; off >>= 1) sm += __shfl_xor(sm, off);
    attn_s[t] = e / sm;
  }
  __syncthreads();
  float acc = 0.f;
  {
    const float* tab = (t < 128) ? ehr_table : onto_all;
    int j = t & 127;
    for (int n = 0; n < kN; ++n)
      acc += attn_s[n] * tab[(size_t)idx_s[n] * 128 + j];
  }
  float ss = mmore_block_sum(acc * acc, red);
  float inv = 1.f / fmaxf(sqrtf(ss), 1e-12f);
  tn[(size_t)bt * 256 + t] = tanhf(acc * inv);
}

// ---------------- dp head GEMM: u[2048][512] = tn@dpWT + dpB ----------------
__global__ __launch_bounds__(256) void mmore_dpgemm(
    const float* __restrict__ tn, const __bf16* __restrict__ dpWT,
    const float* __restrict__ dpB, float* __restrict__ u) {
  int t = threadIdx.x, wave = t >> 6, lane = t & 63, lm = lane & 15, lg = lane >> 4;
  int c0 = blockIdx.x * 128, r0 = blockIdx.y * 32;
  const float* a0 = tn + (size_t)(r0 + lm) * 256 + lg * 8;
  const float* a1 = a0 + 16 * 256;
  const __bf16* bp = dpWT + (size_t)(c0 + wave * 32 + lm) * 256 + lg * 8;
  f32x4 acc[2][2] = {};
  #pragma unroll
  for (int kb = 0; kb < 256; kb += 32) {
    f4 x0 = *(const f4*)(a0 + kb), x1 = *(const f4*)(a0 + kb + 4);
    f4 y0 = *(const f4*)(a1 + kb), y1 = *(const f4*)(a1 + kb + 4);
    bf16x8 af0 = cvt8(x0, x1), af1 = cvt8(y0, y1);
    bf16x8 b0 = *(const bf16x8*)(bp + kb);
    bf16x8 b1 = *(const bf16x8*)(bp + kb + 16 * 256);
    acc[0][0] = MFMA16(af0, b0, acc[0][0], 0, 0, 0);
    acc[0][1] = MFMA16(af0, b1, acc[0][1], 0, 0, 0);
    acc[1][0] = MFMA16(af1, b0, acc[1][0], 0, 0, 0);
    acc[1][1] = MFMA16(af1, b1, acc[1][1], 0, 0, 0);
  }
  #pragma unroll
  for (int mf = 0; mf < 2; ++mf)
    #pragma unroll
    for (int nf = 0; nf < 2; ++nf) {
      int col = c0 + wave * 32 + nf * 16 + lm;
      float bias = (col < kDPL) ? dpB[col] : 0.f;
      #pragma unroll
      for (int j = 0; j < 4; ++j) {
        int row = r0 + mf * 16 + lg * 4 + j;
        u[(size_t)row * 512 + col] = acc[mf][nf][j] + bias;
      }
    }
}

// ---------------- dp softmax over 500 cols ----------------
__global__ __launch_bounds__(128) void mmore_dpsoft(
    const float* __restrict__ u, float* __restrict__ out) {
  int bt = blockIdx.x, t = threadIdx.x;
  __shared__ float red[2];
  float v[4]; float mx = -1e30f;
  #pragma unroll
  for (int i = 0; i < 4; ++i) {
    int c = t + i * 128;
    v[i] = (c < kDPL) ? u[(size_t)bt * 512 + c] : -1e30f;
    mx = fmaxf(mx, v[i]);
  }
  #pragma unroll
  for (int off = 32; off; off >>= 1) mx = fmaxf(mx, __shfl_xor(mx, off));
  if ((t & 63) == 0) red[t >> 6] = mx;
  __syncthreads();
  mx = fmaxf(red[0], red[1]);
  __syncthreads();
  float e[4], s = 0.f;
  #pragma unroll
  for (int i = 0; i < 4; ++i) {
    int c = t + i * 128;
    e[i] = (c < kDPL) ? __expf(v[i] - mx) : 0.f;
    s += e[i];
  }
  #pragma unroll
  for (int off = 32; off; off >>= 1) s += __shfl_xor(s, off);
  if ((t & 63) == 0) red[t >> 6] = s;
  __syncthreads();
  float invS = 1.f / (red[0] + red[1]);
  #pragma unroll
  for (int i = 0; i < 4; ++i) {
    int c = t + i * 128;
    if (c < kDPL) out[(size_t)bt * kDPL + c] = e[i] * invS;
  }
}

extern "C" void kernel_launch(void* const* d_in, const int* in_sizes, int n_in,
                              void* d_out, int out_size, void* d_ws, size_t ws_size,
                              hipStream_t stream) {
  const int*   dxseqs     = (const int*)d_in[0];
  const float* dx_onehot  = (const float*)d_in[1];
  const int*   leaves     = (const int*)d_in[2];
  const int*   ancestors  = (const int*)d_in[3];
  const float* onto_table = (const float*)d_in[4];
  const float* onto_Wa    = (const float*)d_in[5];
  const float* onto_ba    = (const float*)d_in[6];
  const float* onto_Wc    = (const float*)d_in[7];
  const float* onto_bc    = (const float*)d_in[8];
  const float* ehr_table  = (const float*)d_in[9];
  const float* attn_W     = (const float*)d_in[10];
  const float* attn_b     = (const float*)d_in[11];
  const float* comb_W     = (const float*)d_in[12];
  const float* comb_b     = (const float*)d_in[13];
  const float* co_W       = (const float*)d_in[14];
  const float* co_b       = (const float*)d_in[15];
  const float* dp_W       = (const float*)d_in[16];
  const float* dp_b       = (const float*)d_in[17];
  float* out = (float*)d_out;

  // ---- workspace (~26.2 MB) ----
  float* ws = (float*)d_ws;
  size_t off = 0;
  auto alloc = [&](size_t n) { float* p = ws + off; off += n; return p; };
  float* onto_all = alloc((size_t)(kV + 1) * 128);             // 1,280,128
  float* s_sc     = alloc((size_t)kV * kL);                    //    60,000
  float* ehrV     = alloc((size_t)kBT * 128);                  //   262,144
  float* ontoV    = alloc((size_t)kBT * 128);                  //   262,144
  __bf16* Bp      = (__bf16*)alloc((size_t)kNP * kNB * 32 / 2);// 1,362,176 fl
  __bf16* attn_WT = (__bf16*)alloc((size_t)128 * 512 / 2);     //    32,768 fl
  __bf16* dpWT    = (__bf16*)alloc((size_t)512 * 256 / 2);     //    65,536 fl
  __bf16* WaT     = (__bf16*)alloc((size_t)128 * 256 / 2);     //    16,384 fl
  float* peR      = alloc((size_t)(kV + 1) * 128);             // 1,280,128
  float* poR      = alloc((size_t)(kV + 1) * 128);             // 1,280,128
  float* basep    = alloc((size_t)kBT * 128);                  //   262,144
  float* epart    = alloc((size_t)kVT2 * kBT);                 //    81,920
  float* pwred    = alloc((size_t)kBT * 128);                  //   262,144
  float* pc       = alloc(kBT);                                //     2,048
  float* sp       = alloc(kBT);                                //     2,048
  float* term     = alloc(kBT);                                //     2,048
  // time-disjoint aliases in the peR..basep span (2,822,400 fl):
  __bf16* ot_bf = (__bf16*)peR;  // scores input; dead before Btab build
  __bf16* BtabL = (__bf16*)peR;  // linear Btab (1,392,640 fl); built after
                                 // scores, dead after panelize
  float*  cpart = peR;           // xgemm partials (2,785,280 fl); overwrites
                                 // BtabL, dead after creduce
  __bf16* coWT  = (__bf16*)peR;  // loss B (655,360 fl); built after creduce,
                                 // dead before pe-gemm writes peR
  float*  u     = peR;           // dp logits; written after attn reads peR
  float*  tn    = ehrV;          // attn out; written after last ehrV/ontoV reads

  // ---- prep ----
  mmore_cvt_bf16<<<663, 256, 0, stream>>>(onto_table, ot_bf, 10600 * 128);
  mmore_trcvt<<<dim3(2, 8), 256, 0, stream>>>(onto_Wa, WaT, 256, 128, 256);
  mmore_trcvt<<<dim3(4, 8), 256, 0, stream>>>(attn_W, attn_WT, 512, 128, 512);
  mmore_trcvt<<<dim3(2, 32), 256, 0, stream>>>(dp_W, dpWT, 256, kDPL, 256);

  mmore_ehrv<<<kBT, 128, 0, stream>>>(dxseqs, ehr_table, ehrV);
  mmore_scores_mfma<<<(kV * kL) / 32, 256, 0, stream>>>(
      ot_bf, leaves, ancestors, WaT, onto_ba, onto_Wc, onto_bc, s_sc);
  mmore_onto<<<kV + 1, 128, 0, stream>>>(onto_table, ancestors, s_sc, onto_all);
  // Btab (linear) in peR-span (ot_bf dead), then panelize -> Bp
  mmore_trcvt<<<dim3(80, 8), 256, 0, stream>>>(onto_all, BtabL, kV, 128, kLd);
  mmore_brow<<<720, 256, 0, stream>>>(co_W, co_b, BtabL);
  mmore_panelize<<<dim3(kNP, 17), 256, 0, stream>>>(BtabL, Bp);
  mmore_xgemm<<<128 * kXC, 256, 0, stream>>>(dx_onehot, Bp, cpart);
  mmore_creduce<<<kBT, 256, 0, stream>>>(cpart, ontoV, pwred, pc, sp);
  mmore_trcvt<<<dim3(1, 640), 256, 0, stream>>>(co_W, coWT, 128, kV, 128);
  mmore_lossg<<<dim3(kVT2, 64), 256, 0, stream>>>(ehrV, coWT, co_b, epart);
  mmore_lossterm<<<kBT / 16, 256, 0, stream>>>(ehrV, pwred, pc, sp, epart, term);
  mmore_lossfin<<<1, 256, 0, stream>>>(term, out + (size_t)kBT * kDPL);
  mmore_gemm_mfma<<<313, 256, 0, stream>>>(ehr_table, attn_WT, 512, 256, nullptr, peR, kV + 1, 0);
  mmore_gemm_mfma<<<313, 256, 0, stream>>>(onto_all, attn_WT, 512, 384, nullptr, poR, kV + 1, 0);
  mmore_gemm_mfma<<<64, 256, 0, stream>>>(ontoV, attn_WT, 512, 0, nullptr, basep, kBT, 0);
  mmore_gemm_mfma<<<64, 256, 0, stream>>>(ehrV, attn_WT, 512, 128, attn_b, basep, kBT, 1);
  mmore_attn<<<kBT, 256, 0, stream>>>(dxseqs, basep, peR, poR, comb_W, comb_b,
                                      ehr_table, onto_all, tn);
  mmore_dpgemm<<<dim3(4, 64), 256, 0, stream>>>(tn, dpWT, dp_b, u);
  mmore_dpsoft<<<kBT, 128, 0, stream>>>(u, out);
}

// Round 10
// 287.476 us; speedup vs baseline: 1.2421x; 1.0574x over previous
//
#include <hip/hip_runtime.h>
#include <math.h>

typedef float4 f4;
typedef __bf16 bf16x8 __attribute__((ext_vector_type(8)));
typedef float f32x4 __attribute__((ext_vector_type(4)));

static constexpr int kV = 10000, kL = 6, kDPL = 500;
static constexpr int kB = 64, kT = 32, kN = 40, kBT = 2048;
static constexpr int kXC = 5;          // xgemm K-chunks (4 x 2048 + 1824)
static constexpr int kNB = 272;        // xgemm out cols (258 useful)
static constexpr int kLd = 10240;      // Btab/coWT k-/n- pad
static constexpr int kNP = 313;        // panels (10016 k padded)
static constexpr int kVT2 = 40;        // loss v-tiles of 256

#define MFMA16 __builtin_amdgcn_mfma_f32_16x16x32_bf16

typedef const __attribute__((address_space(1))) unsigned int ga_u32;
typedef __attribute__((address_space(3))) unsigned int lds_u32;
__device__ __forceinline__ void gll16(const float* g, float* l) {
  __builtin_amdgcn_global_load_lds((ga_u32*)g, (lds_u32*)l, 16, 0, 0);
}

__device__ __forceinline__ bf16x8 cvt8(f4 a, f4 b) {
  bf16x8 r;
  r[0] = (__bf16)a.x; r[1] = (__bf16)a.y; r[2] = (__bf16)a.z; r[3] = (__bf16)a.w;
  r[4] = (__bf16)b.x; r[5] = (__bf16)b.y; r[6] = (__bf16)b.z; r[7] = (__bf16)b.w;
  return r;
}

// ---------------- fp32 -> bf16 elementwise ----------------
__global__ __launch_bounds__(256) void mmore_cvt_bf16(
    const float* __restrict__ in, __bf16* __restrict__ out, int n) {
  int i = (blockIdx.x * 256 + threadIdx.x) * 8;
  if (i < n) {
    f4 a = *(const f4*)(in + i), b = *(const f4*)(in + i + 4);
    *(bf16x8*)(out + i) = cvt8(a, b);
  }
}

// -------- transpose+cvt: out[n][k] (bf16, k/n-pad zeros) = in[k][n] ---------
__global__ __launch_bounds__(256) void mmore_trcvt(
    const float* __restrict__ in, __bf16* __restrict__ out,
    int K, int N, int Kpad) {
  int t = threadIdx.x;
  int n = blockIdx.y * 16 + (t & 15);
  int kb = (blockIdx.x * 16 + (t >> 4)) * 8;
  bf16x8 r;
  #pragma unroll
  for (int i = 0; i < 8; ++i) {
    int k = kb + i;
    float v = (k < K && n < N) ? in[(size_t)k * N + n] : 0.f;
    r[i] = (__bf16)v;
  }
  *(bf16x8*)(out + (size_t)n * Kpad + kb) = r;
}

// -------- Btab rows 128..271: coW rows (k-contig), cob, ones, zeros ---------
__global__ __launch_bounds__(256) void mmore_brow(
    const float* __restrict__ coW, const float* __restrict__ cob,
    __bf16* __restrict__ Btab) {
  int id = blockIdx.x * 256 + threadIdx.x;
  int rr = id / 1280;               // 0..143
  int kk = (id - rr * 1280) * 8;
  bf16x8 r;
  #pragma unroll
  for (int i = 0; i < 8; ++i) {
    int k = kk + i;
    float v = 0.f;
    if (k < kV) {
      if (rr < 128) v = coW[(size_t)rr * kV + k];
      else if (rr == 128) v = cob[k];
      else if (rr == 129) v = 1.f;
    }
    r[i] = (__bf16)v;
  }
  *(bf16x8*)(Btab + (size_t)(128 + rr) * kLd + kk) = r;
}

// -------- panelize: Bp[S][272][32] = Btab[row][S*32+kk] ---------------------
__global__ __launch_bounds__(256) void mmore_panelize(
    const __bf16* __restrict__ Btab, __bf16* __restrict__ Bp) {
  int t = threadIdx.x;
  int S = blockIdx.x, ry = blockIdx.y;
  int row = ry * 16 + (t >> 4), kk = (t & 15) * 2;
  unsigned v = *(const unsigned*)(Btab + (size_t)row * kLd + S * 32 + kk);
  *(unsigned*)(Bp + ((size_t)S * kNB + row) * 32 + kk) = v;
}

// ---------------- ehrV = l2norm(sum_n ehr_table[dxseqs]) ----------------
__global__ __launch_bounds__(128) void mmore_ehrv(
    const int* __restrict__ dxseqs, const float* __restrict__ ehr_table,
    float* __restrict__ ehrV) {
  int bt = blockIdx.x, t = threadIdx.x;
  const int* row = dxseqs + bt * kN;
  float acc = 0.f;
  for (int n = 0; n < kN; ++n) acc += ehr_table[(size_t)row[n] * 128 + t];
  float v = acc * acc;
  #pragma unroll
  for (int off = 32; off; off >>= 1) v += __shfl_down(v, off);
  __shared__ float red[2];
  if ((t & 63) == 0) red[t >> 6] = v;
  __syncthreads();
  float ss = red[0] + red[1];
  float inv = 1.f / fmaxf(sqrtf(ss), 1e-12f);
  ehrV[bt * 128 + t] = acc * inv;
}

// ---------------- GRAM scores via MFMA ----------------
__global__ __launch_bounds__(256) void mmore_scores_mfma(
    const __bf16* __restrict__ otb, const int* __restrict__ leaves,
    const int* __restrict__ anc, const __bf16* __restrict__ WaT,
    const float* __restrict__ ba, const float* __restrict__ Wc,
    const float* __restrict__ bc, float* __restrict__ s_out) {
  int t = threadIdx.x, wave = t >> 6, lane = t & 63, lm = lane & 15, lg = lane >> 4;
  int r0 = blockIdx.x * 32;
  int rA0 = r0 + lm, rA1 = rA0 + 16;
  int v0 = rA0 / 6, l0 = rA0 - v0 * 6, v1 = rA1 / 6, l1 = rA1 - v1 * 6;
  const __bf16* pL0 = otb + (size_t)leaves[v0 * 6 + l0] * 128;
  const __bf16* pA0 = otb + (size_t)anc[v0 * 6 + l0] * 128;
  const __bf16* pL1 = otb + (size_t)leaves[v1 * 6 + l1] * 128;
  const __bf16* pA1 = otb + (size_t)anc[v1 * 6 + l1] * 128;
  const __bf16* bp = WaT + (size_t)(wave * 32 + lm) * 256 + lg * 8;
  f32x4 acc[2][2] = {};
  #pragma unroll
  for (int kb = 0; kb < 256; kb += 32) {
    int k = kb + lg * 8;
    const __bf16* s0 = (k < 128) ? (pL0 + k) : (pA0 + (k - 128));
    const __bf16* s1 = (k < 128) ? (pL1 + k) : (pA1 + (k - 128));
    bf16x8 a0 = *(const bf16x8*)s0;
    bf16x8 a1 = *(const bf16x8*)s1;
    bf16x8 b0 = *(const bf16x8*)(bp + kb);
    bf16x8 b1 = *(const bf16x8*)(bp + kb + 16 * 256);
    acc[0][0] = MFMA16(a0, b0, acc[0][0], 0, 0, 0);
    acc[0][1] = MFMA16(a0, b1, acc[0][1], 0, 0, 0);
    acc[1][0] = MFMA16(a1, b0, acc[1][0], 0, 0, 0);
    acc[1][1] = MFMA16(a1, b1, acc[1][1], 0, 0, 0);
  }
  __shared__ float red[4][32];
  float bcv = bc[0];
  #pragma unroll
  for (int mf = 0; mf < 2; ++mf) {
    #pragma unroll
    for (int j = 0; j < 4; ++j) {
      float p = 0.f;
      #pragma unroll
      for (int nf = 0; nf < 2; ++nf) {
        int c = wave * 32 + nf * 16 + lm;
        p += tanhf(acc[mf][nf][j] + ba[c]) * Wc[c];
      }
      #pragma unroll
      for (int off = 8; off; off >>= 1) p += __shfl_xor(p, off);
      if (lm == 0) red[wave][mf * 16 + lg * 4 + j] = p;
    }
  }
  __syncthreads();
  if (t < 32) s_out[r0 + t] = red[0][t] + red[1][t] + red[2][t] + red[3][t] + bcv;
}

// ---------------- onto_all[v] = softmax_l(s) . ea ; row V = 0 ----------------
__global__ __launch_bounds__(128) void mmore_onto(
    const float* __restrict__ ot, const int* __restrict__ anc,
    const float* __restrict__ s_in, float* __restrict__ onto_all) {
  int v = blockIdx.x, t = threadIdx.x;
  if (v == kV) { onto_all[(size_t)v * 128 + t] = 0.f; return; }
  __shared__ float sv[kL];
  __shared__ int aidx[kL];
  if (t < kL) { sv[t] = s_in[v * kL + t]; aidx[t] = anc[v * kL + t]; }
  __syncthreads();
  float mx = sv[0];
  #pragma unroll
  for (int l = 1; l < kL; ++l) mx = fmaxf(mx, sv[l]);
  float e[kL], sum = 0.f;
  #pragma unroll
  for (int l = 0; l < kL; ++l) { e[l] = expf(sv[l] - mx); sum += e[l]; }
  float acc = 0.f;
  #pragma unroll
  for (int l = 0; l < kL; ++l)
    acc += (e[l] / sum) * ot[(size_t)aidx[l] * 128 + t];
  onto_all[(size_t)v * 128 + t] = acc;
}

// ===== fused X-GEMM v6: part[chunk][bt][272] = X @ Bp ========================
// Sequential LDS staging: per super-step (BK=256 fp32) each of 16 rows is
// staged by ONE gll16 = 1KB fully-contiguous (prefetcher-friendly streams).
// Source is granule-XOR-permuted per row (lane ^ (row&7)) so LDS reads are
// bank-conflict-free with a LINEAR gll dest (rule #21). During compute, A
// comes from LDS (lgkmcnt) -> the vmem queue holds only L2 Bp loads + the 4
// stage gll16s: ONE long drain per super-step instead of one per group.
// BM=16, 4 waves; grid 128 btiles x 5 chunks = 640 blocks, XCD-swizzled.
__global__ __launch_bounds__(256) void mmore_xgemm(
    const float* __restrict__ X, const __bf16* __restrict__ Bp,
    float* __restrict__ part) {
  __shared__ __align__(16) float Xs[2][16][256];   // 32 KB
  int t = threadIdx.x, w = t >> 6, lane = t & 63, lm = lane & 15, lg = lane >> 4;
  int bid = blockIdx.x;
  int swz = (bid & 7) * 80 + (bid >> 3);     // bijective XCD swizzle
  int btile = swz & 127, chunk = swz >> 7;
  int r0 = btile * 16;
  bool lastc = (chunk == kXC - 1);
  int nSS = lastc ? 7 : 8;                   // super-steps of 256 k
  int kbase = chunk * 2048;
  int f0 = w * 4;
  const __bf16* bp = Bp + ((size_t)(chunk * 64) * kNB + lm) * 32 + lg * 8;
  f32x4 acc[5] = {};

#define XGV6_STAGE(db, S)                                                     \
  {                                                                           \
    _Pragma("unroll")                                                         \
    for (int u = 0; u < 4; ++u) {                                             \
      int row_ = w * 4 + u;                                                   \
      const float* src_ = X + (size_t)(r0 + row_) * kV + kbase + (S) * 256 +  \
                          ((lane ^ (row_ & 7)) << 2);                         \
      gll16(src_, &Xs[db][row_][0]);                                          \
    }                                                                         \
  }

  XGV6_STAGE(0, 0);
  asm volatile("s_waitcnt vmcnt(0)" ::: "memory");
  __builtin_amdgcn_s_barrier();
  int buf = 0;
  for (int S = 0; S < nSS; ++S) {
    if (S + 1 < nSS) {
      if (buf == 0) { XGV6_STAGE(1, S + 1); } else { XGV6_STAGE(0, S + 1); }
    }
    #pragma unroll
    for (int j = 0; j < 8; ++j) {
      int G0 = 8 * j + 2 * lg;
      int sw0 = G0 ^ (lm & 7), sw1 = (G0 + 1) ^ (lm & 7);
      f4 x0 = *(const f4*)&Xs[buf][lm][sw0 * 4];
      f4 x1 = *(const f4*)&Xs[buf][lm][sw1 * 4];
      bf16x8 af = cvt8(x0, x1);
      const __bf16* bs = bp + (size_t)(S * 8 + j) * (kNB * 32);
      acc[0] = MFMA16(af, *(const bf16x8*)(bs + (f0 + 0) * 512), acc[0], 0, 0, 0);
      acc[1] = MFMA16(af, *(const bf16x8*)(bs + (f0 + 1) * 512), acc[1], 0, 0, 0);
      acc[2] = MFMA16(af, *(const bf16x8*)(bs + (f0 + 2) * 512), acc[2], 0, 0, 0);
      acc[3] = MFMA16(af, *(const bf16x8*)(bs + (f0 + 3) * 512), acc[3], 0, 0, 0);
      if (w == 3)
        acc[4] = MFMA16(af, *(const bf16x8*)(bs + 16 * 512), acc[4], 0, 0, 0);
    }
    asm volatile("s_waitcnt vmcnt(0)" ::: "memory");
    __builtin_amdgcn_s_barrier();
    buf ^= 1;
  }
  if (lastc) {  // tail k 9984..9999 direct (Bp panel 312 zero-padded >=10000)
    f4 z = make_float4(0.f, 0.f, 0.f, 0.f), x0 = z, x1 = z;
    if (lg < 2) {
      const float* xp = X + (size_t)(r0 + lm) * kV + 9984 + lg * 8;
      x0 = *(const f4*)xp; x1 = *(const f4*)(xp + 4);
    }
    bf16x8 af = cvt8(x0, x1);
    const __bf16* bs = Bp + ((size_t)312 * kNB + lm) * 32 + lg * 8;
    acc[0] = MFMA16(af, *(const bf16x8*)(bs + (f0 + 0) * 512), acc[0], 0, 0, 0);
    acc[1] = MFMA16(af, *(const bf16x8*)(bs + (f0 + 1) * 512), acc[1], 0, 0, 0);
    acc[2] = MFMA16(af, *(const bf16x8*)(bs + (f0 + 2) * 512), acc[2], 0, 0, 0);
    acc[3] = MFMA16(af, *(const bf16x8*)(bs + (f0 + 3) * 512), acc[3], 0, 0, 0);
    if (w == 3)
      acc[4] = MFMA16(af, *(const bf16x8*)(bs + 16 * 512), acc[4], 0, 0, 0);
  }
  #pragma unroll
  for (int j = 0; j < 4; ++j) {
    int r = r0 + lg * 4 + j;                 // memory row
    int bt = (r & 63) * kT + (r >> 6);       // -> bt index
    size_t o = ((size_t)chunk * kBT + bt) * kNB;
    #pragma unroll
    for (int f = 0; f < 4; ++f) part[o + (f0 + f) * 16 + lm] = acc[f][j];
    if (w == 3) part[o + 256 + lm] = acc[4][j];
  }
#undef XGV6_STAGE
}

// ----- creduce: sum 5 chunk-partials -> ontoV / pwred / pc / sp -------------
__global__ __launch_bounds__(256) void mmore_creduce(
    const float* __restrict__ part, float* __restrict__ ontoV,
    float* __restrict__ pwred, float* __restrict__ pc, float* __restrict__ sp) {
  int bt = blockIdx.x, t = threadIdx.x;
  for (int c = t; c < kNB; c += 256) {
    float a = 0.f;
    #pragma unroll
    for (int ch = 0; ch < kXC; ++ch)
      a += part[((size_t)ch * kBT + bt) * kNB + c];
    if (c < 128) ontoV[(size_t)bt * 128 + c] = a;
    else if (c < 256) pwred[(size_t)bt * 128 + (c - 128)] = a;
    else if (c == 256) pc[bt] = a;
    else if (c == 257) sp[bt] = a;
  }
}

// ----- loss GEMM: epart[vt][bt] = sum_{c in vtile} e^(ehrV@coW + cob) -------
__global__ __launch_bounds__(256) void mmore_lossg(
    const float* __restrict__ ehrV, const __bf16* __restrict__ coWT,
    const float* __restrict__ cob, float* __restrict__ epart) {
  int t = threadIdx.x, wave = t >> 6, lane = t & 63, lm = lane & 15, lg = lane >> 4;
  int vt = blockIdx.x, btile = blockIdx.y;
  int r0 = btile * 32, vb = vt * 256;
  const float* a0 = ehrV + (size_t)(r0 + lm) * 128 + lg * 8;
  const float* a1 = a0 + 16 * 128;
  f32x4 acc[2][4] = {};
  #pragma unroll
  for (int kb = 0; kb < 128; kb += 32) {
    f4 x0 = *(const f4*)(a0 + kb), x1 = *(const f4*)(a0 + kb + 4);
    f4 y0 = *(const f4*)(a1 + kb), y1 = *(const f4*)(a1 + kb + 4);
    bf16x8 af0 = cvt8(x0, x1), af1 = cvt8(y0, y1);
    #pragma unroll
    for (int nf = 0; nf < 4; ++nf) {
      int c = vb + wave * 64 + nf * 16 + lm;
      bf16x8 b = *(const bf16x8*)(coWT + (size_t)c * 128 + kb + lg * 8);
      acc[0][nf] = MFMA16(af0, b, acc[0][nf], 0, 0, 0);
      acc[1][nf] = MFMA16(af1, b, acc[1][nf], 0, 0, 0);
    }
  }
  float se[2][4] = {};
  #pragma unroll
  for (int nf = 0; nf < 4; ++nf) {
    int c = vb + wave * 64 + nf * 16 + lm;
    if (c < kV) {
      float cb = cob[c];
      #pragma unroll
      for (int mf = 0; mf < 2; ++mf)
        #pragma unroll
        for (int j = 0; j < 4; ++j)
          se[mf][j] += __expf(acc[mf][nf][j] + cb);
    }
  }
  __shared__ float red[4][32];
  #pragma unroll
  for (int mf = 0; mf < 2; ++mf)
    #pragma unroll
    for (int j = 0; j < 4; ++j) {
      float v = se[mf][j];
      #pragma unroll
      for (int off = 8; off; off >>= 1) v += __shfl_xor(v, off);
      if (lm == 0) red[wave][mf * 16 + lg * 4 + j] = v;
    }
  __syncthreads();
  if (t < 32)
    epart[(size_t)vt * kBT + r0 + t] =
        red[0][t] + red[1][t] + red[2][t] + red[3][t];
}

// ----- lossterm: term[bt] = (ehrV.pwred + pc) - sp*log(sum epart) -----------
__global__ __launch_bounds__(256) void mmore_lossterm(
    const float* __restrict__ ehrV, const float* __restrict__ pwred,
    const float* __restrict__ pc, const float* __restrict__ sp,
    const float* __restrict__ epart, float* __restrict__ term) {
  int t = threadIdx.x;
  int bt = blockIdx.x * 16 + (t >> 4);
  int sub = t & 15;
  const f4* e = (const f4*)(ehrV + (size_t)bt * 128 + sub * 8);
  const f4* w = (const f4*)(pwred + (size_t)bt * 128 + sub * 8);
  f4 e0 = e[0], e1 = e[1], w0 = w[0], w1 = w[1];
  float d = e0.x * w0.x + e0.y * w0.y + e0.z * w0.z + e0.w * w0.w +
            e1.x * w1.x + e1.y * w1.y + e1.z * w1.z + e1.w * w1.w;
  float S = 0.f;
  for (int vt = sub; vt < kVT2; vt += 16) S += epart[(size_t)vt * kBT + bt];
  #pragma unroll
  for (int off = 8; off; off >>= 1) {
    d += __shfl_xor(d, off); S += __shfl_xor(S, off);
  }
  if (sub == 0) term[bt] = (d + pc[bt]) - sp[bt] * logf(S);
}

__global__ __launch_bounds__(256) void mmore_lossfin(
    const float* __restrict__ term, float* __restrict__ out) {
  int t = threadIdx.x;
  float a = 0.f;
  for (int i = t; i < kBT; i += 256) a += term[i];
  #pragma unroll
  for (int off = 32; off; off >>= 1) a += __shfl_down(a, off);
  __shared__ float red[4];
  if ((t & 63) == 0) red[t >> 6] = a;
  __syncthreads();
  if (t == 0) out[0] = -(10.f / 64.f) * (red[0] + red[1] + red[2] + red[3]);
}

// ---------------- generic MFMA: C[M][128] (+=) A[M][128] @ WT[n][ldWT]+koff --
__global__ __launch_bounds__(256) void mmore_gemm_mfma(
    const float* __restrict__ A, const __bf16* __restrict__ WT,
    int ldWT, int koff, const float* __restrict__ bias,
    float* __restrict__ C, int M, int accumulate) {
  int t = threadIdx.x, wave = t >> 6, lane = t & 63, lm = lane & 15, lg = lane >> 4;
  int r0 = blockIdx.x * 32;
  int row0 = r0 + lm, row1 = row0 + 16;
  bool ok0 = row0 < M, ok1 = row1 < M;
  const float* a0 = A + (size_t)row0 * 128 + lg * 8;
  const float* a1 = A + (size_t)row1 * 128 + lg * 8;
  const __bf16* bp = WT + (size_t)(wave * 32 + lm) * ldWT + koff + lg * 8;
  int ld16 = 16 * ldWT;
  f32x4 acc[2][2] = {};
  #pragma unroll
  for (int kb = 0; kb < 128; kb += 32) {
    f4 x0 = make_float4(0, 0, 0, 0), x1 = x0, y0 = x0, y1 = x0;
    if (ok0) { x0 = *(const f4*)(a0 + kb); x1 = *(const f4*)(a0 + kb + 4); }
    if (ok1) { y0 = *(const f4*)(a1 + kb); y1 = *(const f4*)(a1 + kb + 4); }
    bf16x8 af0 = cvt8(x0, x1), af1 = cvt8(y0, y1);
    bf16x8 b0 = *(const bf16x8*)(bp + kb);
    bf16x8 b1 = *(const bf16x8*)(bp + kb + ld16);
    acc[0][0] = MFMA16(af0, b0, acc[0][0], 0, 0, 0);
    acc[0][1] = MFMA16(af0, b1, acc[0][1], 0, 0, 0);
    acc[1][0] = MFMA16(af1, b0, acc[1][0], 0, 0, 0);
    acc[1][1] = MFMA16(af1, b1, acc[1][1], 0, 0, 0);
  }
  #pragma unroll
  for (int mf = 0; mf < 2; ++mf)
    #pragma unroll
    for (int nf = 0; nf < 2; ++nf) {
      int col = wave * 32 + nf * 16 + lm;
      #pragma unroll
      for (int j = 0; j < 4; ++j) {
        int row = r0 + mf * 16 + lg * 4 + j;
        if (row < M) {
          float v = acc[mf][nf][j];
          if (bias) v += bias[col];
          if (accumulate) v += C[(size_t)row * 128 + col];
          C[(size_t)row * 128 + col] = v;
        }
      }
    }
}

// ---------------- per-(b,t): Bahdanau attention -> tn = tanh(l2norm(vs2)) ----
__device__ __forceinline__ float mmore_block_sum(float v, float* red) {
  int t = threadIdx.x;
  #pragma unroll
  for (int off = 32; off; off >>= 1) v += __shfl_down(v, off);
  if ((t & 63) == 0) red[t >> 6] = v;
  __syncthreads();
  if (t == 0) red[0] = red[0] + red[1] + red[2] + red[3];
  __syncthreads();
  return red[0];
}

__global__ __launch_bounds__(256) void mmore_attn(
    const int* __restrict__ dxseqs, const float* __restrict__ base,
    const float* __restrict__ pe, const float* __restrict__ po,
    const float* __restrict__ combW, const float* __restrict__ combB,
    const float* __restrict__ ehr_table, const float* __restrict__ onto_all,
    float* __restrict__ tn) {
  __shared__ float base_s[128];
  __shared__ int idx_s[kN];
  __shared__ float scp[kN][2];
  __shared__ float attn_s[64];
  __shared__ float red[4];
  int bt = blockIdx.x, t = threadIdx.x;
  if (t < 128) base_s[t] = base[bt * 128 + t];
  if (t < kN) idx_s[t] = dxseqs[bt * kN + t];
  __syncthreads();
  int c = t & 127, half = t >> 7, wid = t >> 6, lane = t & 63;
  float cw = combW[c];
  for (int n2 = 0; n2 < kN / 2; ++n2) {
    int n = n2 * 2 + half;
    int id = idx_s[n];
    float x = base_s[c] + pe[(size_t)id * 128 + c] + po[(size_t)id * 128 + c];
    float val = tanhf(x) * cw;
    #pragma unroll
    for (int off = 32; off; off >>= 1) val += __shfl_down(val, off);
    if (lane == 0) scp[n][wid & 1] = val;
  }
  __syncthreads();
  if (t < 64) {
    float s = (t < kN) ? (scp[t][0] + scp[t][1] + combB[0]) : -1e30f;
    float mx = s;
    #pragma unroll
    for (int off = 32; off; off >>= 1) mx = fmaxf(mx, __shfl_xor(mx, off));
    float e = (t < kN) ? __expf(s - mx) : 0.f;
    float sm = e;
    #pragma unroll
    for (int off = 32; off; off >>= 1) sm += __shfl_xor(sm, off);
    attn_s[t] = e / sm;
  }
  __syncthreads();
  float acc = 0.f;
  {
    const float* tab = (t < 128) ? ehr_table : onto_all;
    int j = t & 127;
    for (int n = 0; n < kN; ++n)
      acc += attn_s[n] * tab[(size_t)idx_s[n] * 128 + j];
  }
  float ss = mmore_block_sum(acc * acc, red);
  float inv = 1.f / fmaxf(sqrtf(ss), 1e-12f);
  tn[(size_t)bt * 256 + t] = tanhf(acc * inv);
}

// ---------------- dp head GEMM: u[2048][512] = tn@dpWT + dpB ----------------
__global__ __launch_bounds__(256) void mmore_dpgemm(
    const float* __restrict__ tn, const __bf16* __restrict__ dpWT,
    const float* __restrict__ dpB, float* __restrict__ u) {
  int t = threadIdx.x, wave = t >> 6, lane = t & 63, lm = lane & 15, lg = lane >> 4;
  int c0 = blockIdx.x * 128, r0 = blockIdx.y * 32;
  const float* a0 = tn + (size_t)(r0 + lm) * 256 + lg * 8;
  const float* a1 = a0 + 16 * 256;
  const __bf16* bp = dpWT + (size_t)(c0 + wave * 32 + lm) * 256 + lg * 8;
  f32x4 acc[2][2] = {};
  #pragma unroll
  for (int kb = 0; kb < 256; kb += 32) {
    f4 x0 = *(const f4*)(a0 + kb), x1 = *(const f4*)(a0 + kb + 4);
    f4 y0 = *(const f4*)(a1 + kb), y1 = *(const f4*)(a1 + kb + 4);
    bf16x8 af0 = cvt8(x0, x1), af1 = cvt8(y0, y1);
    bf16x8 b0 = *(const bf16x8*)(bp + kb);
    bf16x8 b1 = *(const bf16x8*)(bp + kb + 16 * 256);
    acc[0][0] = MFMA16(af0, b0, acc[0][0], 0, 0, 0);
    acc[0][1] = MFMA16(af0, b1, acc[0][1], 0, 0, 0);
    acc[1][0] = MFMA16(af1, b0, acc[1][0], 0, 0, 0);
    acc[1][1] = MFMA16(af1, b1, acc[1][1], 0, 0, 0);
  }
  #pragma unroll
  for (int mf = 0; mf < 2; ++mf)
    #pragma unroll
    for (int nf = 0; nf < 2; ++nf) {
      int col = c0 + wave * 32 + nf * 16 + lm;
      float bias = (col < kDPL) ? dpB[col] : 0.f;
      #pragma unroll
      for (int j = 0; j < 4; ++j) {
        int row = r0 + mf * 16 + lg * 4 + j;
        u[(size_t)row * 512 + col] = acc[mf][nf][j] + bias;
      }
    }
}

// ---------------- dp softmax over 500 cols ----------------
__global__ __launch_bounds__(128) void mmore_dpsoft(
    const float* __restrict__ u, float* __restrict__ out) {
  int bt = blockIdx.x, t = threadIdx.x;
  __shared__ float red[2];
  float v[4]; float mx = -1e30f;
  #pragma unroll
  for (int i = 0; i < 4; ++i) {
    int c = t + i * 128;
    v[i] = (c < kDPL) ? u[(size_t)bt * 512 + c] : -1e30f;
    mx = fmaxf(mx, v[i]);
  }
  #pragma unroll
  for (int off = 32; off; off >>= 1) mx = fmaxf(mx, __shfl_xor(mx, off));
  if ((t & 63) == 0) red[t >> 6] = mx;
  __syncthreads();
  mx = fmaxf(red[0], red[1]);
  __syncthreads();
  float e[4], s = 0.f;
  #pragma unroll
  for (int i = 0; i < 4; ++i) {
    int c = t + i * 128;
    e[i] = (c < kDPL) ? __expf(v[i] - mx) : 0.f;
    s += e[i];
  }
  #pragma unroll
  for (int off = 32; off; off >>= 1) s += __shfl_xor(s, off);
  if ((t & 63) == 0) red[t >> 6] = s;
  __syncthreads();
  float invS = 1.f / (red[0] + red[1]);
  #pragma unroll
  for (int i = 0; i < 4; ++i) {
    int c = t + i * 128;
    if (c < kDPL) out[(size_t)bt * kDPL + c] = e[i] * invS;
  }
}

extern "C" void kernel_launch(void* const* d_in, const int* in_sizes, int n_in,
                              void* d_out, int out_size, void* d_ws, size_t ws_size,
                              hipStream_t stream) {
  const int*   dxseqs     = (const int*)d_in[0];
  const float* dx_onehot  = (const float*)d_in[1];
  const int*   leaves     = (const int*)d_in[2];
  const int*   ancestors  = (const int*)d_in[3];
  const float* onto_table = (const float*)d_in[4];
  const float* onto_Wa    = (const float*)d_in[5];
  const float* onto_ba    = (const float*)d_in[6];
  const float* onto_Wc    = (const float*)d_in[7];
  const float* onto_bc    = (const float*)d_in[8];
  const float* ehr_table  = (const float*)d_in[9];
  const float* attn_W     = (const float*)d_in[10];
  const float* attn_b     = (const float*)d_in[11];
  const float* comb_W     = (const float*)d_in[12];
  const float* comb_b     = (const float*)d_in[13];
  const float* co_W       = (const float*)d_in[14];
  const float* co_b       = (const float*)d_in[15];
  const float* dp_W       = (const float*)d_in[16];
  const float* dp_b       = (const float*)d_in[17];
  float* out = (float*)d_out;

  // ---- workspace (~26.2 MB) ----
  float* ws = (float*)d_ws;
  size_t off = 0;
  auto alloc = [&](size_t n) { float* p = ws + off; off += n; return p; };
  float* onto_all = alloc((size_t)(kV + 1) * 128);             // 1,280,128
  float* s_sc     = alloc((size_t)kV * kL);                    //    60,000
  float* ehrV     = alloc((size_t)kBT * 128);                  //   262,144
  float* ontoV    = alloc((size_t)kBT * 128);                  //   262,144
  __bf16* Bp      = (__bf16*)alloc((size_t)kNP * kNB * 32 / 2);// 1,362,176 fl
  __bf16* attn_WT = (__bf16*)alloc((size_t)128 * 512 / 2);     //    32,768 fl
  __bf16* dpWT    = (__bf16*)alloc((size_t)512 * 256 / 2);     //    65,536 fl
  __bf16* WaT     = (__bf16*)alloc((size_t)128 * 256 / 2);     //    16,384 fl
  float* peR      = alloc((size_t)(kV + 1) * 128);             // 1,280,128
  float* poR      = alloc((size_t)(kV + 1) * 128);             // 1,280,128
  float* basep    = alloc((size_t)kBT * 128);                  //   262,144
  float* epart    = alloc((size_t)kVT2 * kBT);                 //    81,920
  float* pwred    = alloc((size_t)kBT * 128);                  //   262,144
  float* pc       = alloc(kBT);                                //     2,048
  float* sp       = alloc(kBT);                                //     2,048
  float* term     = alloc(kBT);                                //     2,048
  // time-disjoint aliases in the peR..basep span (2,822,400 fl):
  __bf16* ot_bf = (__bf16*)peR;  // scores input; dead before Btab build
  __bf16* BtabL = (__bf16*)peR;  // linear Btab (1,392,640 fl); built after
                                 // scores, dead after panelize
  float*  cpart = peR;           // xgemm partials (2,785,280 fl); overwrites
                                 // BtabL, dead after creduce
  __bf16* coWT  = (__bf16*)peR;  // loss B (655,360 fl); built after creduce,
                                 // dead before pe-gemm writes peR
  float*  u     = peR;           // dp logits; written after attn reads peR
  float*  tn    = ehrV;          // attn out; written after last ehrV/ontoV reads

  // ---- prep ----
  mmore_cvt_bf16<<<663, 256, 0, stream>>>(onto_table, ot_bf, 10600 * 128);
  mmore_trcvt<<<dim3(2, 8), 256, 0, stream>>>(onto_Wa, WaT, 256, 128, 256);
  mmore_trcvt<<<dim3(4, 8), 256, 0, stream>>>(attn_W, attn_WT, 512, 128, 512);
  mmore_trcvt<<<dim3(2, 32), 256, 0, stream>>>(dp_W, dpWT, 256, kDPL, 256);

  mmore_ehrv<<<kBT, 128, 0, stream>>>(dxseqs, ehr_table, ehrV);
  mmore_scores_mfma<<<(kV * kL) / 32, 256, 0, stream>>>(
      ot_bf, leaves, ancestors, WaT, onto_ba, onto_Wc, onto_bc, s_sc);
  mmore_onto<<<kV + 1, 128, 0, stream>>>(onto_table, ancestors, s_sc, onto_all);
  // Btab (linear) in peR-span (ot_bf dead), then panelize -> Bp
  mmore_trcvt<<<dim3(80, 8), 256, 0, stream>>>(onto_all, BtabL, kV, 128, kLd);
  mmore_brow<<<720, 256, 0, stream>>>(co_W, co_b, BtabL);
  mmore_panelize<<<dim3(kNP, 17), 256, 0, stream>>>(BtabL, Bp);
  mmore_xgemm<<<128 * kXC, 256, 0, stream>>>(dx_onehot, Bp, cpart);
  mmore_creduce<<<kBT, 256, 0, stream>>>(cpart, ontoV, pwred, pc, sp);
  mmore_trcvt<<<dim3(1, 640), 256, 0, stream>>>(co_W, coWT, 128, kV, 128);
  mmore_lossg<<<dim3(kVT2, 64), 256, 0, stream>>>(ehrV, coWT, co_b, epart);
  mmore_lossterm<<<kBT / 16, 256, 0, stream>>>(ehrV, pwred, pc, sp, epart, term);
  mmore_lossfin<<<1, 256, 0, stream>>>(term, out + (size_t)kBT * kDPL);
  mmore_gemm_mfma<<<313, 256, 0, stream>>>(ehr_table, attn_WT, 512, 256, nullptr, peR, kV + 1, 0);
  mmore_gemm_mfma<<<313, 256, 0, stream>>>(onto_all, attn_WT, 512, 384, nullptr, poR, kV + 1, 0);
  mmore_gemm_mfma<<<64, 256, 0, stream>>>(ontoV, attn_WT, 512, 0, nullptr, basep, kBT, 0);
  mmore_gemm_mfma<<<64, 256, 0, stream>>>(ehrV, attn_WT, 512, 128, attn_b, basep, kBT, 1);
  mmore_attn<<<kBT, 256, 0, stream>>>(dxseqs, basep, peR, poR, comb_W, comb_b,
                                      ehr_table, onto_all, tn);
  mmore_dpgemm<<<dim3(4, 64), 256, 0, stream>>>(tn, dpWT, dp_b, u);
  mmore_dpsoft<<<kBT, 128, 0, stream>>>(u, out);
}